// Round 4
// baseline (2929.554 us; speedup 1.0000x reference)
//
#include <hip/hip_runtime.h>

// Inputs: fp32. Outputs: fp32 (established round 3: PASSED).

constexpr int BB = 4;
constexpr int NN = 4096;
constexpr int M1 = 2048;
constexpr int M2 = 512;

// Exact fp32 squared distance matching numpy's (dx*dx) + (dy*dy), no fma contraction.
__device__ __forceinline__ float d2_exact(float dx, float dy) {
    return __fadd_rn(__fmul_rn(dx, dx), __fmul_rn(dy, dy));
}

// DPP with bound_ctrl=1 (invalid source lanes read 0 — zero key always loses,
// all real keys > 0). Proven ladder: 0x111/0x112/0x114/0x118 row_shr 1/2/4/8,
// 0x142 row_bcast15 (lane15->row1, lane31->row2, lane47->row3), 0x143
// row_bcast31 (lane31->rows 2,3) -> full-wave max lands at lane 63.
// After 0x111+0x112 the 4-lane-quad max sits at every lane with (l&3)==3.
template<int CTRL>
__device__ __forceinline__ unsigned long long dpp64z(unsigned long long v) {
    unsigned lo = (unsigned)__builtin_amdgcn_update_dpp(0, (int)(unsigned)v, CTRL, 0xF, 0xF, true);
    unsigned hi = (unsigned)__builtin_amdgcn_update_dpp(0, (int)(unsigned)(v >> 32), CTRL, 0xF, 0xF, true);
    return ((unsigned long long)hi << 32) | (unsigned long long)lo;
}
template<int CTRL>
__device__ __forceinline__ float dppfz(float v) {
    return __uint_as_float((unsigned)__builtin_amdgcn_update_dpp(
        0, (int)__float_as_uint(v), CTRL, 0xF, 0xF, true));
}
// Keyed max with (x,y) payload riding the same select. Bit-preserving moves only.
template<int CTRL>
__device__ __forceinline__ void max1p(unsigned long long& k, float& x, float& y) {
    unsigned long long ok = dpp64z<CTRL>(k);
    float ox = dppfz<CTRL>(x);
    float oy = dppfz<CTRL>(y);
    bool g = ok > k;
    k = g ? ok : k;
    x = g ? ox : x;
    y = g ? oy : y;
}
__device__ __forceinline__ float readlanef(float v, int l) {
    return __uint_as_float((unsigned)__builtin_amdgcn_readlane((int)__float_as_uint(v), l));
}

// Branchless r-th-set-bit of a u64 (r < popc(m)); popcount binary search.
__device__ __forceinline__ int nthbit64(unsigned long long m, int r) {
    unsigned lo = (unsigned)m, hi = (unsigned)(m >> 32);
    int p = __popc(lo);
    bool a = r >= p;
    unsigned h = a ? hi : lo;
    int b = a ? 32 : 0;
    r -= a ? p : 0;
    p = __popc(h & 0xFFFFu);
    a = r >= p; h = a ? (h >> 16) : h; b += a ? 16 : 0; r -= a ? p : 0; h &= 0xFFFFu;
    p = __popc(h & 0xFFu);
    a = r >= p; h = a ? (h >> 8) : h;  b += a ? 8 : 0;  r -= a ? p : 0; h &= 0xFFu;
    p = __popc(h & 0xFu);
    a = r >= p; h = a ? (h >> 4) : h;  b += a ? 4 : 0;  r -= a ? p : 0; h &= 0xFu;
    p = __popc(h & 0x3u);
    a = r >= p; h = a ? (h >> 2) : h;  b += a ? 2 : 0;  r -= a ? p : 0; h &= 0x3u;
    a = r >= (int)(h & 1u);
    b += a ? 1 : 0;
    return b;
}

// ---------------------------------------------------------------------------
// lf = tanh(tanh(x@W1+b1)@W2+b2) -> out (fp32); also
// y1[j,f] = lf_j@c1W[0:64] + zones_j*c1W[64] + pos_j@c1W[65:67] + c1b (fp32 ws)
// ---------------------------------------------------------------------------
__global__ __launch_bounds__(256) void k_lf_y1(
    const float2* __restrict__ x, const float* __restrict__ zones,
    const float* __restrict__ W1, const float* __restrict__ b1,
    const float* __restrict__ W2, const float* __restrict__ b2,
    const float* __restrict__ c1W, const float* __restrict__ c1b,
    float* __restrict__ out_lf, float* __restrict__ y1)
{
    __shared__ float sh[4][64];
    __shared__ float sl[4][64];
    int tid = threadIdx.x;
    int p = tid >> 6, f = tid & 63;
    size_t pt = (size_t)blockIdx.x * 4 + p;
    float2 xv = x[pt];
    float hid = tanhf(xv.x * W1[f] + xv.y * W1[64 + f] + b1[f]);
    sh[p][f] = hid;
    __syncthreads();
    float acc = b2[f];
#pragma unroll
    for (int c = 0; c < 64; ++c) acc += sh[p][c] * W2[c * 64 + f];
    float lf = tanhf(acc);
    sl[p][f] = lf;
    out_lf[pt * 64 + f] = lf;
    __syncthreads();
    float acc2 = c1b[f] + zones[pt] * c1W[64 * 64 + f]
               + xv.x * c1W[65 * 64 + f] + xv.y * c1W[66 * 64 + f];
#pragma unroll
    for (int c = 0; c < 64; ++c) acc2 += sl[p][c] * c1W[c * 64 + f];
    y1[pt * 64 + f] = acc2;
}

// ---------------------------------------------------------------------------
// Lazy chunked FPS, v3: 16-pt chunks, 4 lanes/chunk, 16 chunks per rescan
// pass -> steady state is ONE pass per round.
//
// Exactness invariants (unchanged from PASSED v1/v2):
//  * md[p] = min over picked centers of d2_exact(p-c); min is order-free.
//  * Skip rule: boxd2(B,c) from rn-monotone ops => boxd2 <= d2(p,c) for all
//    chunk points; boxd2 >= bmd (= chunk max md) => nothing in the chunk
//    changes (md values or cached best key).
//  * Unique u64 key = bits(md)<<32 | (0xFFFFFFFF - orig_idx): FIRST-index
//    tie-break; global max over chunk maxima == reference argmax.
//  * Winner's chunk always rescans next round (boxd2 = 0 < bmd>0).
//  * Chunk partition (scatter atomics order) is result-invariant.
// ---------------------------------------------------------------------------

__device__ __forceinline__ unsigned part1by1(unsigned v) {
    v = (v | (v << 8)) & 0x00FF00FFu;
    v = (v | (v << 4)) & 0x0F0F0F0Fu;
    v = (v | (v << 2)) & 0x33333333u;
    v = (v | (v << 1)) & 0x55555555u;
    return v;
}
__device__ __forceinline__ unsigned mortcid(float px, float py, float lx, float ly,
                                            float sx, float sy) {
    int ix = (int)((px - lx) * sx); ix = ix < 0 ? 0 : (ix > 31 ? 31 : ix);
    int iy = (int)((py - ly) * sy); iy = iy < 0 ? 0 : (iy > 31 ? 31 : iy);
    return part1by1((unsigned)ix) | (part1by1((unsigned)iy) << 1);
}

constexpr int PTS = 17;                  // chunk stride in float4 (16 + 1 pad)

// Bucket N points into NCH chunks of 16 (32x32 Morton-cell counting sort,
// sorted slots sliced into 16s). All 256 threads. PT slot (c*PTS + s&15) =
// {x, y, md=1e10, bits(0xFFFFFFFF-idx)}.
template<int N, int NCH>
__device__ void build_chunks(const float2* __restrict__ src,
                             float4* PT, float4* BBX,
                             unsigned* HIST, float* red,
                             int tid, int lane, int wv)
{
    // ---- global bbox (containment only)
    float lx = 1e30f, hx = -1e30f, ly = 1e30f, hy = -1e30f;
    for (int i = tid; i < N; i += 256) {
        float2 q = src[i];
        lx = fminf(lx, q.x); hx = fmaxf(hx, q.x);
        ly = fminf(ly, q.y); hy = fmaxf(hy, q.y);
    }
#pragma unroll
    for (int d = 1; d < 64; d <<= 1) {
        lx = fminf(lx, __shfl_xor(lx, d)); hx = fmaxf(hx, __shfl_xor(hx, d));
        ly = fminf(ly, __shfl_xor(ly, d)); hy = fmaxf(hy, __shfl_xor(hy, d));
    }
    if (lane == 0) {
        red[wv * 4 + 0] = lx; red[wv * 4 + 1] = hx;
        red[wv * 4 + 2] = ly; red[wv * 4 + 3] = hy;
    }
    __syncthreads();
    lx = fminf(fminf(red[0], red[4]),  fminf(red[8],  red[12]));
    hx = fmaxf(fmaxf(red[1], red[5]),  fmaxf(red[9],  red[13]));
    ly = fminf(fminf(red[2], red[6]),  fminf(red[10], red[14]));
    hy = fmaxf(fmaxf(red[3], red[7]),  fmaxf(red[11], red[15]));
    float sx = 31.999f / fmaxf(hx - lx, 1e-20f);
    float sy = 31.999f / fmaxf(hy - ly, 1e-20f);

    // ---- histogram over 1024 Morton cells
    for (int i = tid; i < 1024; i += 256) HIST[i] = 0u;
    __syncthreads();
    for (int i = tid; i < N; i += 256) {
        float2 q = src[i];
        atomicAdd(&HIST[mortcid(q.x, q.y, lx, ly, sx, sy)], 1u);
    }
    __syncthreads();

    // ---- exclusive prefix (thread t owns bins 4t..4t+3) — proven v1 code
    unsigned b0 = HIST[4 * tid], b1 = HIST[4 * tid + 1],
             b2 = HIST[4 * tid + 2], b3 = HIST[4 * tid + 3];
    unsigned s = b0 + b1 + b2 + b3;
    unsigned incl = s;
#pragma unroll
    for (int d = 1; d < 64; d <<= 1) {
        unsigned o = __shfl_up(incl, d);
        if (lane >= d) incl += o;
    }
    if (lane == 63) ((unsigned*)red)[wv] = incl;
    __syncthreads();
    unsigned woff = 0;
    for (int w = 0; w < wv; ++w) woff += ((unsigned*)red)[w];
    unsigned e = woff + incl - s;
    HIST[4 * tid]     = e;
    HIST[4 * tid + 1] = e + b0;
    HIST[4 * tid + 2] = e + b0 + b1;
    HIST[4 * tid + 3] = e + b0 + b1 + b2;
    __syncthreads();

    // ---- scatter (HIST doubles as cursor); slot order result-invariant.
    for (int i = tid; i < N; i += 256) {
        float2 q = src[i];
        unsigned slot = atomicAdd(&HIST[mortcid(q.x, q.y, lx, ly, sx, sy)], 1u);
        PT[(slot >> 4) * PTS + (slot & 15)] =
            make_float4(q.x, q.y, 1e10f, __uint_as_float(0xFFFFFFFFu - (unsigned)i));
    }
    __syncthreads();

    // ---- per-chunk bbox: one thread per chunk (NCH <= 256)
    if (tid < NCH) {
        float x0 = 1e30f, x1 = -1e30f, y0 = 1e30f, y1 = -1e30f;
#pragma unroll
        for (int j = 0; j < 16; ++j) {
            float4 q = PT[tid * PTS + j];
            x0 = fminf(x0, q.x); x1 = fmaxf(x1, q.x);
            y0 = fminf(y0, q.y); y1 = fmaxf(y1, q.y);
        }
        BBX[tid] = make_float4(x0, y0, x1, y1);
    }
    __syncthreads();
}

// Round loop: single wave (wave 0), no barriers. Lane l owns chunks
// {64j + l}, j < NMASK. Quad q (=lane>>2) rescans the (q + 16*pass)-th
// affected chunk. centl[0] must hold c0.
template<int M, int NCH>
__device__ void fps_rounds(float4* __restrict__ PT, uint4* __restrict__ CB,
                           const float4* __restrict__ BBX,
                           float2* __restrict__ centl, int lane)
{
#pragma clang fp contract(off)
    constexpr int NMASK = NCH / 64;
    float4 bb[NMASK];
    unsigned long long ckey[NMASK];
    float cbx[NMASK], cby[NMASK], bmd[NMASK];
#pragma unroll
    for (int j = 0; j < NMASK; ++j) {
        bb[j] = BBX[j * 64 + lane];
        ckey[j] = 0ull; cbx[j] = 0.0f; cby[j] = 0.0f;
        bmd[j] = __uint_as_float(0x7F800000u);   // +inf => round-1 full rescan
    }
    float2 c0 = centl[0];
    float cx = c0.x, cy = c0.y;
    int q4 = lane >> 2, s4 = lane & 3;

    for (int it = 1; it < M; ++it) {
        // ---- bound tests + ballots (rn-monotone => bd2 <= d2(p,c))
        unsigned long long bal[NMASK];
        bool resc[NMASK];
#pragma unroll
        for (int j = 0; j < NMASK; ++j) {
            float dx = fmaxf(fmaxf(bb[j].x - cx, cx - bb[j].z), 0.0f);
            float dy = fmaxf(fmaxf(bb[j].y - cy, cy - bb[j].w), 0.0f);
            float bd2 = d2_exact(dx, dy);
            resc[j] = bd2 < bmd[j];
            bal[j] = __ballot(resc[j]);
        }
        int P[NMASK + 1];
        P[0] = 0;
#pragma unroll
        for (int j = 0; j < NMASK; ++j) P[j + 1] = P[j] + __popcll(bal[j]);
        int total = P[NMASK];

        // ---- cached-best ladder FIRST (independent of rescan; overlaps its
        //      LDS latency). Rescanned chunks masked to 0 — rescan re-covers.
        unsigned long long zk = 0ull;
        float zx = 0.0f, zy = 0.0f;
#pragma unroll
        for (int j = 0; j < NMASK; ++j) {
            unsigned long long kj = resc[j] ? 0ull : ckey[j];
            bool g = kj > zk;
            zk = g ? kj : zk; zx = g ? cbx[j] : zx; zy = g ? cby[j] : zy;
        }
        max1p<0x111>(zk, zx, zy); max1p<0x112>(zk, zx, zy);
        max1p<0x114>(zk, zx, zy); max1p<0x118>(zk, zx, zy);
        max1p<0x142>(zk, zx, zy); max1p<0x143>(zk, zx, zy);   // -> lane 63

        // ---- rescan passes: 16 chunks per pass, 4 lanes per chunk
        unsigned long long rbk = 0ull;
        float rbx = 0.0f, rby = 0.0f;
        for (int pass = 0; pass * 16 < total; ++pass) {
            int r = q4 + pass * 16;
            unsigned long long m = bal[0];
            int chb = 0, rr = r;
#pragma unroll
            for (int j = 1; j < NMASK; ++j) {
                bool adv = r >= P[j];
                m = adv ? bal[j] : m;
                chb = adv ? j * 64 : chb;
                rr = adv ? r - P[j] : rr;
            }
            bool act = r < total;
            unsigned long long key = 0ull;
            float px = 0.0f, py = 0.0f;
            if (act) {
                int c = chb + nthbit64(m, rr);
                int base = c * PTS + s4;
#pragma unroll
                for (int jj = 0; jj < 4; ++jj) {
                    float4 qv = PT[base + jj * 4];
                    float d2v = d2_exact(qv.x - cx, qv.y - cy);
                    float nmd = fminf(qv.z, d2v);
                    PT[base + jj * 4].z = nmd;
                    unsigned long long kk =
                        ((unsigned long long)__float_as_uint(nmd) << 32)
                        | (unsigned long long)__float_as_uint(qv.w);
                    if (kk > key) { key = kk; px = qv.x; py = qv.y; }
                }
                // quad reduce (chunk best at s4==3), then continue to lane 63
                max1p<0x111>(key, px, py); max1p<0x112>(key, px, py);
                if (s4 == 3)
                    CB[c] = make_uint4((unsigned)key, (unsigned)(key >> 32),
                                       __float_as_uint(px), __float_as_uint(py));
            } else {
                max1p<0x111>(key, px, py); max1p<0x112>(key, px, py);
            }
            max1p<0x114>(key, px, py); max1p<0x118>(key, px, py);
            max1p<0x142>(key, px, py); max1p<0x143>(key, px, py);
            bool g = key > rbk;          // lane 63 carries the real fold
            rbk = g ? key : rbk; rbx = g ? px : rbx; rby = g ? py : rby;
        }

        // ---- deferred owner refresh: issue now, consume after fold
        uint4 nc[NMASK];
#pragma unroll
        for (int j = 0; j < NMASK; ++j) {
            nc[j] = make_uint4(0u, 0u, 0u, 0u);
            if (resc[j]) nc[j] = CB[j * 64 + lane];
        }

        // ---- fold rescan best into cached best (lane 63 valid)
        bool gf = rbk > zk;
        zx = gf ? rbx : zx; zy = gf ? rby : zy;
        float wx = readlanef(zx, 63);
        float wy = readlanef(zy, 63);
        if (lane == 0) centl[it] = make_float2(wx, wy);
        cx = wx; cy = wy;

        // ---- apply refresh (ordered after same-wave CB writes)
#pragma unroll
        for (int j = 0; j < NMASK; ++j) {
            if (resc[j]) {
                ckey[j] = ((unsigned long long)nc[j].y << 32)
                        | (unsigned long long)nc[j].x;
                cbx[j] = __uint_as_float(nc[j].z);
                cby[j] = __uint_as_float(nc[j].w);
                bmd[j] = __uint_as_float(nc[j].y);
            }
        }
    }
}

// ---------------------------------------------------------------------------
// Fused FPS stage1 (4096 -> 2048, 256 chunks) + stage2 (2048 -> 512,
// 128 chunks). 256 threads: all 4 waves build/copy, wave 0 runs rounds.
// ---------------------------------------------------------------------------
__global__ __launch_bounds__(256, 1) void k_fps_fused(
    const float2* __restrict__ pos, float* __restrict__ p1out,
    float* __restrict__ p2out)
{
    __shared__ float4 PT[256 * PTS];     // 68 KB padded chunk slots
    __shared__ float4 BBX[256];          // 4 KB chunk bbox {x0,y0,x1,y1}
    __shared__ uint4  CB[256];           // 4 KB chunk best {klo,khi,xb,yb}
    __shared__ unsigned HIST[1024];      // 4 KB sort bins/cursors
    __shared__ float2 C1[M1];            // 16 KB
    __shared__ float2 C2[M2];            // 4 KB
    __shared__ float red[16];            // reduce scratch
    int tid = threadIdx.x, lane = tid & 63, wv = tid >> 6;
    const float2* p = pos + (size_t)blockIdx.x * NN;

    build_chunks<NN, 256>(p, PT, BBX, HIST, red, tid, lane, wv);
    if (tid == 0) C1[0] = p[0];
    __syncthreads();
    if (wv == 0) fps_rounds<M1, 256>(PT, CB, BBX, C1, lane);
    __syncthreads();
    float2* o1 = (float2*)(p1out + (size_t)blockIdx.x * M1 * 2);
    for (int i = tid; i < M1; i += 256) o1[i] = C1[i];

    build_chunks<M1, 128>((const float2*)C1, PT, BBX, HIST, red, tid, lane, wv);
    if (tid == 0) C2[0] = C1[0];
    __syncthreads();
    if (wv == 0) fps_rounds<M2, 128>(PT, CB, BBX, C2, lane);
    __syncthreads();
    float2* o2 = (float2*)(p2out + (size_t)blockIdx.x * M2 * 2);
    for (int i = tid; i < M2; i += 256) o2[i] = C2[i];
}

// ---------------------------------------------------------------------------
// Set abstraction: h[i,f] = max_{j: d2(j,i)<=r2} y[j,f]  -  ctr_i @ W_rel.
// ---------------------------------------------------------------------------
__global__ __launch_bounds__(256) void k_sa(
    const float2* __restrict__ candpos, const float* __restrict__ y,
    const float* __restrict__ ctr, const float* __restrict__ W,
    int NP, int F, int relrow, float r2, float* __restrict__ hout)
{
    __shared__ int cnt;
    __shared__ int list[4096];
    int tid = threadIdx.x;
    int b = blockIdx.y;
    size_t crow = (size_t)b * gridDim.x + blockIdx.x;
    if (tid == 0) cnt = 0;
    __syncthreads();
    float cx = ctr[crow * 2], cy = ctr[crow * 2 + 1];
    const float2* cp = candpos + (size_t)b * NP;
    for (int j = tid; j < NP; j += 256) {
        float2 pj = cp[j];
        float d2 = d2_exact(pj.x - cx, pj.y - cy);
        if (d2 <= r2) { int t = atomicAdd(&cnt, 1); list[t] = j; }
    }
    __syncthreads();
    int n = cnt;
    for (int f = tid; f < F; f += 256) {
        float m = -3.0e38f;
        for (int t = 0; t < n; ++t)
            m = fmaxf(m, y[((size_t)b * NP + list[t]) * F + f]);
        float ct = cx * W[(size_t)relrow * F + f] + cy * W[(size_t)(relrow + 1) * F + f];
        hout[crow * F + f] = m - ct;
    }
}

// ---------------------------------------------------------------------------
// y2[j,f] = h1_j @ c2W[0:64] + pos_j @ c2W[64:66] + c2b
// ---------------------------------------------------------------------------
__global__ __launch_bounds__(128) void k_y2(
    const float* __restrict__ h1, const float* __restrict__ p1,
    const float* __restrict__ W, const float* __restrict__ bb,
    float* __restrict__ y2)
{
    __shared__ float sh[64];
    size_t row = blockIdx.x;
    int f = threadIdx.x;
    if (f < 64) sh[f] = h1[row * 64 + f];
    __syncthreads();
    float acc = bb[f] + p1[row * 2] * W[64 * 128 + f]
              + p1[row * 2 + 1] * W[65 * 128 + f];
#pragma unroll
    for (int c = 0; c < 64; ++c) acc += sh[c] * W[c * 128 + f];
    y2[row * 128 + f] = acc;
}

// ---------------------------------------------------------------------------
// g[i,f] = [h2_i, pos_i] @ c3W + c3b; partial max over 8 rows/thread.
// ---------------------------------------------------------------------------
__global__ __launch_bounds__(256) void k_g(
    const float* __restrict__ h2, const float* __restrict__ p2,
    const float* __restrict__ W3, const float* __restrict__ b3,
    float* __restrict__ part)
{
    int f = blockIdx.x * 256 + threadIdx.x;
    int b = blockIdx.z;
    int i0 = blockIdx.y * 8;
    float acc[8];
    float bbv = b3[f];
#pragma unroll
    for (int ii = 0; ii < 8; ++ii) acc[ii] = bbv;
    const float* hrow = h2 + ((size_t)b * M2 + i0) * 128;
    for (int c = 0; c < 128; ++c) {
        float w = W3[(size_t)c * 1024 + f];
#pragma unroll
        for (int ii = 0; ii < 8; ++ii) acc[ii] += hrow[ii * 128 + c] * w;
    }
    float wx = W3[(size_t)128 * 1024 + f];
    float wy = W3[(size_t)129 * 1024 + f];
    const float* prow = p2 + ((size_t)b * M2 + i0) * 2;
    float m = -3.0e38f;
#pragma unroll
    for (int ii = 0; ii < 8; ++ii) {
        float g = acc[ii] + prow[ii * 2] * wx + prow[ii * 2 + 1] * wy;
        m = fmaxf(m, g);
    }
    part[((size_t)b * 64 + blockIdx.y) * 1024 + f] = m;
}

__global__ __launch_bounds__(256) void k_gmax(const float* __restrict__ part,
                                              float* __restrict__ outg)
{
    int f = blockIdx.x * 256 + threadIdx.x;   // 0..4095
    int b = f >> 10, fl = f & 1023;
    float m = -3.0e38f;
#pragma unroll 8
    for (int ig = 0; ig < 64; ++ig)
        m = fmaxf(m, part[((size_t)b * 64 + ig) * 1024 + fl]);
    outg[f] = m;
}

extern "C" void kernel_launch(void* const* d_in, const int* in_sizes, int n_in,
                              void* d_out, int out_size, void* d_ws, size_t ws_size,
                              hipStream_t stream)
{
    const float* x    = (const float*)d_in[0];
    const float* zon  = (const float*)d_in[1];
    const float* lfW1 = (const float*)d_in[2];
    const float* lfb1 = (const float*)d_in[3];
    const float* lfW2 = (const float*)d_in[4];
    const float* lfb2 = (const float*)d_in[5];
    const float* c1W  = (const float*)d_in[6];
    const float* c1b  = (const float*)d_in[7];
    const float* c2W  = (const float*)d_in[8];
    const float* c2b  = (const float*)d_in[9];
    const float* c3W  = (const float*)d_in[10];
    const float* c3b  = (const float*)d_in[11];
    float* out = (float*)d_out;

    // Workspace (fp32). "big" (4 MB) reused: y1 -> y2 -> part.
    char* w = (char*)d_ws;
    float* big = (float*)w;                    w += (size_t)BB * NN * 64 * 4;   // 4 MB
    float* p1  = (float*)w;                    w += (size_t)BB * M1 * 2 * 4;
    float* h1  = (float*)w;                    w += (size_t)BB * M1 * 64 * 4;   // 2 MB
    float* p2  = (float*)w;                    w += (size_t)BB * M2 * 2 * 4;
    float* h2  = (float*)w;                    w += (size_t)BB * M2 * 128 * 4;  // 1 MB
    float* y1 = big, * y2 = big, * part = big;

    k_lf_y1<<<BB * NN / 4, 256, 0, stream>>>((const float2*)x, zon, lfW1, lfb1,
                                             lfW2, lfb2, c1W, c1b, out, y1);
    k_fps_fused<<<BB, 256, 0, stream>>>((const float2*)x, p1, p2);
    k_sa<<<dim3(M1, BB), 256, 0, stream>>>((const float2*)x, y1, p1, c1W,
                                           NN, 64, 65, 0.25f, h1);
    k_y2<<<BB * M1, 128, 0, stream>>>(h1, p1, c2W, c2b, y2);
    k_sa<<<dim3(M2, BB), 256, 0, stream>>>((const float2*)p1, y2, p2, c2W,
                                           M1, 128, 64, 1.0f, h2);
    k_g<<<dim3(4, 64, BB), 256, 0, stream>>>(h2, p2, c3W, c3b, part);
    k_gmax<<<16, 256, 0, stream>>>(part, out + (size_t)BB * NN * 64);
}

// Round 5
// 2237.662 us; speedup vs baseline: 1.3092x; 1.3092x over previous
//
#include <hip/hip_runtime.h>

// Inputs: fp32. Outputs: fp32 (established round 3: PASSED).

constexpr int BB = 4;
constexpr int NN = 4096;
constexpr int M1 = 2048;
constexpr int M2 = 512;

typedef float v2f __attribute__((ext_vector_type(2)));

// Exact fp32 squared distance matching numpy's (dx*dx) + (dy*dy), no fma contraction.
__device__ __forceinline__ float d2_exact(float dx, float dy) {
    return __fadd_rn(__fmul_rn(dx, dx), __fmul_rn(dy, dy));
}

// DPP with bound_ctrl=1 (invalid source lanes read 0 — zero keys always lose,
// all real keys > 0). Proven ladder: 0x111/0x112/0x114/0x118 row_shr 1/2/4/8,
// 0x142 row_bcast15, 0x143 row_bcast31 -> full-wave result at lane 63.
template<int CTRL>
__device__ __forceinline__ unsigned long long dpp64z(unsigned long long v) {
    unsigned lo = (unsigned)__builtin_amdgcn_update_dpp(0, (int)(unsigned)v, CTRL, 0xF, 0xF, true);
    unsigned hi = (unsigned)__builtin_amdgcn_update_dpp(0, (int)(unsigned)(v >> 32), CTRL, 0xF, 0xF, true);
    return ((unsigned long long)hi << 32) | (unsigned long long)lo;
}
template<int CTRL>
__device__ __forceinline__ float dppfz(float v) {
    return __uint_as_float((unsigned)__builtin_amdgcn_update_dpp(
        0, (int)__float_as_uint(v), CTRL, 0xF, 0xF, true));
}
__device__ __forceinline__ float readlanef(float v, int l) {
    return __uint_as_float((unsigned)__builtin_amdgcn_readlane((int)__float_as_uint(v), l));
}

// (top1, top2) combine with CTRL partner, coords riding as payload.
// Key select logic is R0's proven pairc; payloads follow the same booleans
// with bit-preserving moves only.
template<int CTRL>
__device__ __forceinline__ void pairp(unsigned long long& t1, float& x1, float& y1,
                                      unsigned long long& t2, float& x2, float& y2) {
    unsigned long long o1 = dpp64z<CTRL>(t1);
    unsigned long long o2 = dpp64z<CTRL>(t2);
    float ox1 = dppfz<CTRL>(x1), oy1 = dppfz<CTRL>(y1);
    float ox2 = dppfz<CTRL>(x2), oy2 = dppfz<CTRL>(y2);
    bool g = o1 > t1;
    unsigned long long m1 = g ? o1 : t1;
    float mx = g ? ox1 : x1, my = g ? oy1 : y1;
    unsigned long long sm = g ? t1 : o1;
    float sx = g ? x1 : ox1, sy = g ? y1 : oy1;
    unsigned long long cn = g ? o2 : t2;
    float nx = g ? ox2 : x2, ny = g ? oy2 : y2;
    bool h = cn > sm;
    t2 = h ? cn : sm; x2 = h ? nx : sx; y2 = h ? ny : sy;
    t1 = m1; x1 = mx; y1 = my;
}

// Branchless coord reconstruction from a key's embedded slot index.
// s in [0, 2*PP2); k = s>>1 selects the v2f register (3-level tree, no scratch).
template<int PP2>
__device__ __forceinline__ void sel_pt(const v2f (&px2)[PP2], const v2f (&py2)[PP2],
                                       unsigned s, float& X, float& Y) {
    unsigned k = s >> 1;
    v2f vx, vy;
    if constexpr (PP2 == 8) {
        v2f x0 = (k & 1) ? px2[1] : px2[0], x1 = (k & 1) ? px2[3] : px2[2];
        v2f x2 = (k & 1) ? px2[5] : px2[4], x3 = (k & 1) ? px2[7] : px2[6];
        v2f y0 = (k & 1) ? py2[1] : py2[0], y1 = (k & 1) ? py2[3] : py2[2];
        v2f y2 = (k & 1) ? py2[5] : py2[4], y3 = (k & 1) ? py2[7] : py2[6];
        v2f xa = (k & 2) ? x1 : x0, xb = (k & 2) ? x3 : x2;
        v2f ya = (k & 2) ? y1 : y0, yb = (k & 2) ? y3 : y2;
        vx = (k & 4) ? xb : xa; vy = (k & 4) ? yb : ya;
    } else {
        v2f x0 = (k & 1) ? px2[1] : px2[0], x1 = (k & 1) ? px2[3] : px2[2];
        v2f y0 = (k & 1) ? py2[1] : py2[0], y1 = (k & 1) ? py2[3] : py2[2];
        vx = (k & 2) ? x1 : x0; vy = (k & 2) ? y1 : y0;
    }
    X = (s & 1) ? vx.y : vx.x;
    Y = (s & 1) ? vy.y : vy.x;
}

// ---------------------------------------------------------------------------
// lf = tanh(tanh(x@W1+b1)@W2+b2) -> out (fp32); also
// y1[j,f] = lf_j@c1W[0:64] + zones_j*c1W[64] + pos_j@c1W[65:67] + c1b (fp32 ws)
// ---------------------------------------------------------------------------
__global__ __launch_bounds__(256) void k_lf_y1(
    const float2* __restrict__ x, const float* __restrict__ zones,
    const float* __restrict__ W1, const float* __restrict__ b1,
    const float* __restrict__ W2, const float* __restrict__ b2,
    const float* __restrict__ c1W, const float* __restrict__ c1b,
    float* __restrict__ out_lf, float* __restrict__ y1)
{
    __shared__ float sh[4][64];
    __shared__ float sl[4][64];
    int tid = threadIdx.x;
    int p = tid >> 6, f = tid & 63;
    size_t pt = (size_t)blockIdx.x * 4 + p;
    float2 xv = x[pt];
    float hid = tanhf(xv.x * W1[f] + xv.y * W1[64 + f] + b1[f]);
    sh[p][f] = hid;
    __syncthreads();
    float acc = b2[f];
#pragma unroll
    for (int c = 0; c < 64; ++c) acc += sh[p][c] * W2[c * 64 + f];
    float lf = tanhf(acc);
    sl[p][f] = lf;
    out_lf[pt * 64 + f] = lf;
    __syncthreads();
    float acc2 = c1b[f] + zones[pt] * c1W[64 * 64 + f]
               + xv.x * c1W[65 * 64 + f] + xv.y * c1W[66 * 64 + f];
#pragma unroll
    for (int c = 0; c < 64; ++c) acc2 += sl[p][c] * c1W[c * 64 + f];
    y1[pt * 64 + f] = acc2;
}

// ---------------------------------------------------------------------------
// FPS core: R0's proven 4-wave structure (cooperative 16-pt/lane scan, top-2
// speculation, parity-buffered single barrier per round) with ONE change:
// winner/runner-up COORDS ride the DPP ladder as payload, so the post-combine
// indexed LDS reads (PTSl[jw], PTSl[jr]) and the PTS staging array are gone.
// Bit-exact vs reference scan:
//   md[j] = fmin(md[j], d2_exact(j, c)); argmax w/ FIRST-index tie-break via
//   unique u64 key = bits(md)<<32 | (0xFFFFFFFF - j).
// If d2_exact(r1, w1) >= md_r1 the next reference pick is exactly r1 -> emit 2.
// ---------------------------------------------------------------------------
template<int M, int PPT>
__device__ __forceinline__ void fps_core(
    const float2* __restrict__ src, float2* __restrict__ centl,
    uint4 (&slk)[2][4][2], int tid, int lane, int wv)
{
#pragma clang fp contract(off)
    constexpr int PP2 = PPT / 2;
    v2f px2[PP2], py2[PP2], md2[PP2];
#pragma unroll
    for (int k = 0; k < PP2; ++k) {
        float2 a = src[tid + (2 * k) * 256];
        float2 b = src[tid + (2 * k + 1) * 256];
        px2[k] = (v2f){a.x, b.x};
        py2[k] = (v2f){a.y, b.y};
        md2[k] = (v2f){1e10f, 1e10f};
    }
    float2 c0 = src[0];
    if (tid == 0) centl[0] = c0;

    float c1x = c0.x, c1y = c0.y, c2x = 0.0f, c2y = 0.0f;
    bool two = false;
    int it = 1;
    unsigned rc = 0;
    while (it < M) {
        int par = (int)(rc & 1u); ++rc;
        // ---- packed md update by pending center(s); rn per half == scalar rn
        v2f vcx = (v2f){c1x, c1x}, vcy = (v2f){c1y, c1y};
#pragma unroll
        for (int k = 0; k < PP2; ++k) {
            v2f dx = px2[k] - vcx, dy = py2[k] - vcy;
            v2f d2 = (dx * dx) + (dy * dy);          // contract off => exact
            md2[k] = __builtin_elementwise_min(md2[k], d2);
        }
        if (two) {
            v2f wcx = (v2f){c2x, c2x}, wcy = (v2f){c2y, c2y};
#pragma unroll
            for (int k = 0; k < PP2; ++k) {
                v2f dx = px2[k] - wcx, dy = py2[k] - wcy;
                v2f d2 = (dx * dx) + (dy * dy);
                md2[k] = __builtin_elementwise_min(md2[k], d2);
            }
        }
        // ---- per-lane top-2 keys (verbatim R0) ----
        unsigned long long t1 = 0ull, t2 = 0ull;
#pragma unroll
        for (int s = 0; s < PPT; ++s) {
            float mq = (s & 1) ? md2[s >> 1].y : md2[s >> 1].x;
            unsigned long long key =
                ((unsigned long long)__float_as_uint(mq) << 32)
                | (unsigned long long)(0xFFFFFFFFu - (unsigned)(tid + s * 256));
            bool g = key > t1;
            unsigned long long ns = g ? t1 : (key > t2 ? key : t2);
            t1 = g ? key : t1;
            t2 = ns;
        }
        // ---- reconstruct coords for this lane's top-2 (slot from key low32)
        float x1p, y1p, x2p, y2p;
        unsigned base = 0xFFFFFFFFu - (unsigned)tid;
        sel_pt<PP2>(px2, py2, (base - (unsigned)t1) >> 8, x1p, y1p);
        sel_pt<PP2>(px2, py2, (base - (unsigned)t2) >> 8, x2p, y2p);
        // ---- wave pair ladder with payload -> lane 63 ----
        pairp<0x111>(t1, x1p, y1p, t2, x2p, y2p);
        pairp<0x112>(t1, x1p, y1p, t2, x2p, y2p);
        pairp<0x114>(t1, x1p, y1p, t2, x2p, y2p);
        pairp<0x118>(t1, x1p, y1p, t2, x2p, y2p);
        pairp<0x142>(t1, x1p, y1p, t2, x2p, y2p);
        pairp<0x143>(t1, x1p, y1p, t2, x2p, y2p);
        if (lane == 63) {
            slk[par][wv][0] = make_uint4((unsigned)t1, (unsigned)(t1 >> 32),
                                         __float_as_uint(x1p), __float_as_uint(y1p));
            slk[par][wv][1] = make_uint4((unsigned)t2, (unsigned)(t2 >> 32),
                                         __float_as_uint(x2p), __float_as_uint(y2p));
        }
        __syncthreads();                   // the only barrier per round
        // ---- cross-wave pair tree over 4 wave entries (lanes 0-3) ----
        uint4 e1 = slk[par][lane & 3][0];
        uint4 e2 = slk[par][lane & 3][1];
        unsigned long long a1 = ((unsigned long long)e1.y << 32) | (unsigned long long)e1.x;
        unsigned long long a2 = ((unsigned long long)e2.y << 32) | (unsigned long long)e2.x;
        float ax1 = __uint_as_float(e1.z), ay1 = __uint_as_float(e1.w);
        float ax2 = __uint_as_float(e2.z), ay2 = __uint_as_float(e2.w);
        if (lane >= 4) { a1 = 0ull; a2 = 0ull; }
        pairp<0x111>(a1, ax1, ay1, a2, ax2, ay2);
        pairp<0x112>(a1, ax1, ay1, a2, ax2, ay2);   // result at lane 3
        unsigned mdr_u = (unsigned)__builtin_amdgcn_readlane((int)(unsigned)(a2 >> 32), 3);
        float wx = readlanef(ax1, 3), wy = readlanef(ay1, 3);
        float rx = readlanef(ax2, 3), ry = readlanef(ay2, 3);
        float mdr = __uint_as_float(mdr_u);
        float ddx = rx - wx, ddy = ry - wy;
        float dd = (ddx * ddx) + (ddy * ddy);    // contract off => exact rn
        bool dbl = (it + 1 < M) && (dd >= mdr);  // uniform
        if (tid == 0) {
            centl[it] = make_float2(wx, wy);
            if (dbl) centl[it + 1] = make_float2(rx, ry);
        }
        c1x = wx; c1y = wy; c2x = rx; c2y = ry;
        two = dbl;
        it += dbl ? 2 : 1;
    }
}

// ---------------------------------------------------------------------------
// Fused FPS stage1 (4096 -> 2048) + stage2 (2048 -> 512); stage2 input is
// stage1's LDS-resident cent1. 256 threads (4 waves, 1/SIMD).
// ---------------------------------------------------------------------------
__global__ __launch_bounds__(256, 1) void k_fps_fused(
    const float2* __restrict__ pos, float* __restrict__ p1out,
    float* __restrict__ p2out)
{
    __shared__ float2 cent1[M1];          // 16 KB
    __shared__ float2 cent2[M2];          // 4 KB
    __shared__ uint4 slk[2][4][2];        // 256 B parity pair buffers
    int tid = threadIdx.x, lane = tid & 63, wv = tid >> 6;
    const float2* p = pos + (size_t)blockIdx.x * NN;

    fps_core<M1, NN / 256>(p, cent1, slk, tid, lane, wv);
    __syncthreads();                      // cent1 complete
    float2* o1 = (float2*)(p1out + (size_t)blockIdx.x * M1 * 2);
    for (int i = tid; i < M1; i += 256) o1[i] = cent1[i];

    fps_core<M2, M1 / 256>(cent1, cent2, slk, tid, lane, wv);
    __syncthreads();                      // cent2 complete
    float2* o2 = (float2*)(p2out + (size_t)blockIdx.x * M2 * 2);
    for (int i = tid; i < M2; i += 256) o2[i] = cent2[i];
}

// ---------------------------------------------------------------------------
// Set abstraction: h[i,f] = max_{j: d2(j,i)<=r2} y[j,f]  -  ctr_i @ W_rel.
// ---------------------------------------------------------------------------
__global__ __launch_bounds__(256) void k_sa(
    const float2* __restrict__ candpos, const float* __restrict__ y,
    const float* __restrict__ ctr, const float* __restrict__ W,
    int NP, int F, int relrow, float r2, float* __restrict__ hout)
{
    __shared__ int cnt;
    __shared__ int list[4096];
    int tid = threadIdx.x;
    int b = blockIdx.y;
    size_t crow = (size_t)b * gridDim.x + blockIdx.x;
    if (tid == 0) cnt = 0;
    __syncthreads();
    float cx = ctr[crow * 2], cy = ctr[crow * 2 + 1];
    const float2* cp = candpos + (size_t)b * NP;
    for (int j = tid; j < NP; j += 256) {
        float2 pj = cp[j];
        float d2 = d2_exact(pj.x - cx, pj.y - cy);
        if (d2 <= r2) { int t = atomicAdd(&cnt, 1); list[t] = j; }
    }
    __syncthreads();
    int n = cnt;
    for (int f = tid; f < F; f += 256) {
        float m = -3.0e38f;
        for (int t = 0; t < n; ++t)
            m = fmaxf(m, y[((size_t)b * NP + list[t]) * F + f]);
        float ct = cx * W[(size_t)relrow * F + f] + cy * W[(size_t)(relrow + 1) * F + f];
        hout[crow * F + f] = m - ct;
    }
}

// ---------------------------------------------------------------------------
// y2[j,f] = h1_j @ c2W[0:64] + pos_j @ c2W[64:66] + c2b
// ---------------------------------------------------------------------------
__global__ __launch_bounds__(128) void k_y2(
    const float* __restrict__ h1, const float* __restrict__ p1,
    const float* __restrict__ W, const float* __restrict__ bb,
    float* __restrict__ y2)
{
    __shared__ float sh[64];
    size_t row = blockIdx.x;
    int f = threadIdx.x;
    if (f < 64) sh[f] = h1[row * 64 + f];
    __syncthreads();
    float acc = bb[f] + p1[row * 2] * W[64 * 128 + f]
              + p1[row * 2 + 1] * W[65 * 128 + f];
#pragma unroll
    for (int c = 0; c < 64; ++c) acc += sh[c] * W[c * 128 + f];
    y2[row * 128 + f] = acc;
}

// ---------------------------------------------------------------------------
// g[i,f] = [h2_i, pos_i] @ c3W + c3b; partial max over 8 rows/thread.
// ---------------------------------------------------------------------------
__global__ __launch_bounds__(256) void k_g(
    const float* __restrict__ h2, const float* __restrict__ p2,
    const float* __restrict__ W3, const float* __restrict__ b3,
    float* __restrict__ part)
{
    int f = blockIdx.x * 256 + threadIdx.x;
    int b = blockIdx.z;
    int i0 = blockIdx.y * 8;
    float acc[8];
    float bbv = b3[f];
#pragma unroll
    for (int ii = 0; ii < 8; ++ii) acc[ii] = bbv;
    const float* hrow = h2 + ((size_t)b * M2 + i0) * 128;
    for (int c = 0; c < 128; ++c) {
        float w = W3[(size_t)c * 1024 + f];
#pragma unroll
        for (int ii = 0; ii < 8; ++ii) acc[ii] += hrow[ii * 128 + c] * w;
    }
    float wx = W3[(size_t)128 * 1024 + f];
    float wy = W3[(size_t)129 * 1024 + f];
    const float* prow = p2 + ((size_t)b * M2 + i0) * 2;
    float m = -3.0e38f;
#pragma unroll
    for (int ii = 0; ii < 8; ++ii) {
        float g = acc[ii] + prow[ii * 2] * wx + prow[ii * 2 + 1] * wy;
        m = fmaxf(m, g);
    }
    part[((size_t)b * 64 + blockIdx.y) * 1024 + f] = m;
}

__global__ __launch_bounds__(256) void k_gmax(const float* __restrict__ part,
                                              float* __restrict__ outg)
{
    int f = blockIdx.x * 256 + threadIdx.x;   // 0..4095
    int b = f >> 10, fl = f & 1023;
    float m = -3.0e38f;
#pragma unroll 8
    for (int ig = 0; ig < 64; ++ig)
        m = fmaxf(m, part[((size_t)b * 64 + ig) * 1024 + fl]);
    outg[f] = m;
}

extern "C" void kernel_launch(void* const* d_in, const int* in_sizes, int n_in,
                              void* d_out, int out_size, void* d_ws, size_t ws_size,
                              hipStream_t stream)
{
    const float* x    = (const float*)d_in[0];
    const float* zon  = (const float*)d_in[1];
    const float* lfW1 = (const float*)d_in[2];
    const float* lfb1 = (const float*)d_in[3];
    const float* lfW2 = (const float*)d_in[4];
    const float* lfb2 = (const float*)d_in[5];
    const float* c1W  = (const float*)d_in[6];
    const float* c1b  = (const float*)d_in[7];
    const float* c2W  = (const float*)d_in[8];
    const float* c2b  = (const float*)d_in[9];
    const float* c3W  = (const float*)d_in[10];
    const float* c3b  = (const float*)d_in[11];
    float* out = (float*)d_out;

    // Workspace (fp32). "big" (4 MB) reused: y1 -> y2 -> part.
    char* w = (char*)d_ws;
    float* big = (float*)w;                    w += (size_t)BB * NN * 64 * 4;   // 4 MB
    float* p1  = (float*)w;                    w += (size_t)BB * M1 * 2 * 4;
    float* h1  = (float*)w;                    w += (size_t)BB * M1 * 64 * 4;   // 2 MB
    float* p2  = (float*)w;                    w += (size_t)BB * M2 * 2 * 4;
    float* h2  = (float*)w;                    w += (size_t)BB * M2 * 128 * 4;  // 1 MB
    float* y1 = big, * y2 = big, * part = big;

    k_lf_y1<<<BB * NN / 4, 256, 0, stream>>>((const float2*)x, zon, lfW1, lfb1,
                                             lfW2, lfb2, c1W, c1b, out, y1);
    k_fps_fused<<<BB, 256, 0, stream>>>((const float2*)x, p1, p2);
    k_sa<<<dim3(M1, BB), 256, 0, stream>>>((const float2*)x, y1, p1, c1W,
                                           NN, 64, 65, 0.25f, h1);
    k_y2<<<BB * M1, 128, 0, stream>>>(h1, p1, c2W, c2b, y2);
    k_sa<<<dim3(M2, BB), 256, 0, stream>>>((const float2*)p1, y2, p2, c2W,
                                           M1, 128, 64, 1.0f, h2);
    k_g<<<dim3(4, 64, BB), 256, 0, stream>>>(h2, p2, c3W, c3b, part);
    k_gmax<<<16, 256, 0, stream>>>(part, out + (size_t)BB * NN * 64);
}

// Round 6
// 1842.837 us; speedup vs baseline: 1.5897x; 1.2142x over previous
//
#include <hip/hip_runtime.h>

// Inputs: fp32. Outputs: fp32 (established round 3: PASSED).

constexpr int BB = 4;
constexpr int NN = 4096;
constexpr int M1 = 2048;
constexpr int M2 = 512;

typedef float v2f __attribute__((ext_vector_type(2)));

// Exact fp32 squared distance matching numpy's (dx*dx) + (dy*dy), no fma contraction.
__device__ __forceinline__ float d2_exact(float dx, float dy) {
    return __fadd_rn(__fmul_rn(dx, dx), __fmul_rn(dy, dy));
}

// DPP with bound_ctrl=1 (invalid source lanes read 0 — zero keys always lose,
// all real keys > 0). Wave ladder (R0-proven): 0x111/0x112/0x114/0x118
// row_shr 1/2/4/8, 0x142 row_bcast15, 0x143 row_bcast31 -> result at lane 63.
// Quad levels: 0xB1 = quad_perm [1,0,3,2] (xor1), 0x4E = quad_perm [2,3,0,1]
// (xor2) — butterfly within each 4-lane quad, result in ALL lanes.
template<int CTRL>
__device__ __forceinline__ unsigned long long dpp64z(unsigned long long v) {
    unsigned lo = (unsigned)__builtin_amdgcn_update_dpp(0, (int)(unsigned)v, CTRL, 0xF, 0xF, true);
    unsigned hi = (unsigned)__builtin_amdgcn_update_dpp(0, (int)(unsigned)(v >> 32), CTRL, 0xF, 0xF, true);
    return ((unsigned long long)hi << 32) | (unsigned long long)lo;
}
// (top1, top2) u64 pair combine with CTRL partner pair. Keys unique. (R11/R12 proven.)
template<int CTRL>
__device__ __forceinline__ void pairc(unsigned long long& t1, unsigned long long& t2) {
    unsigned long long o1 = dpp64z<CTRL>(t1);
    unsigned long long o2 = dpp64z<CTRL>(t2);
    bool g = o1 > t1;
    unsigned long long m1 = g ? o1 : t1;
    unsigned long long sm = g ? t1 : o1;
    unsigned long long cn = g ? o2 : t2;
    t2 = cn > sm ? cn : sm;
    t1 = m1;
}

// ---------------------------------------------------------------------------
// lf = tanh(tanh(x@W1+b1)@W2+b2) -> out (fp32); also
// y1[j,f] = lf_j@c1W[0:64] + zones_j*c1W[64] + pos_j@c1W[65:67] + c1b (fp32 ws)
// ---------------------------------------------------------------------------
__global__ __launch_bounds__(256) void k_lf_y1(
    const float2* __restrict__ x, const float* __restrict__ zones,
    const float* __restrict__ W1, const float* __restrict__ b1,
    const float* __restrict__ W2, const float* __restrict__ b2,
    const float* __restrict__ c1W, const float* __restrict__ c1b,
    float* __restrict__ out_lf, float* __restrict__ y1)
{
    __shared__ float sh[4][64];
    __shared__ float sl[4][64];
    int tid = threadIdx.x;
    int p = tid >> 6, f = tid & 63;
    size_t pt = (size_t)blockIdx.x * 4 + p;
    float2 xv = x[pt];
    float hid = tanhf(xv.x * W1[f] + xv.y * W1[64 + f] + b1[f]);
    sh[p][f] = hid;
    __syncthreads();
    float acc = b2[f];
#pragma unroll
    for (int c = 0; c < 64; ++c) acc += sh[p][c] * W2[c * 64 + f];
    float lf = tanhf(acc);
    sl[p][f] = lf;
    out_lf[pt * 64 + f] = lf;
    __syncthreads();
    float acc2 = c1b[f] + zones[pt] * c1W[64 * 64 + f]
               + xv.x * c1W[65 * 64 + f] + xv.y * c1W[66 * 64 + f];
#pragma unroll
    for (int c = 0; c < 64; ++c) acc2 += sl[p][c] * c1W[c * 64 + f];
    y1[pt * 64 + f] = acc2;
}

// ---------------------------------------------------------------------------
// FPS core: R0's proven 4-wave structure (top-2 speculation, parity-buffered
// single barrier per round). Two symmetric chain cuts vs R0:
//  (1) per-lane top-2 scan is an associative sorted-pair merge TREE (keys
//      unique -> (max,second) reduce is associative): chain ~30 ops vs 16x5.
//  (2) cross-wave combine via quad_perm butterfly: every lane reads one of
//      the 4 wave entries (b128, conflict-free) and 2 quad merges leave the
//      GLOBAL top-2 in every lane -> no readlanes, no SGPR broadcast chain.
// Bit-exact vs reference scan:
//   md[j] = fmin(md[j], d2_exact(j, c)); argmax w/ FIRST-index tie-break via
//   unique u64 key = bits(md)<<32 | (0xFFFFFFFF - j).
// If d2_exact(r1, w1) >= md_r1 the next reference pick is exactly r1 (all
// other keys < key_r1; updates only lower md; ties resolve by ~j) -> emit 2.
// ---------------------------------------------------------------------------
template<int M, int PPT>
__device__ __forceinline__ void fps_core(
    const float2* __restrict__ src, const float2* __restrict__ PTSl,
    float2* __restrict__ centl, uint4 (&slk)[2][4],
    int tid, int lane, int wv)
{
#pragma clang fp contract(off)
    constexpr int PP2 = PPT / 2;
    v2f px2[PP2], py2[PP2], md2[PP2];
#pragma unroll
    for (int k = 0; k < PP2; ++k) {
        float2 a = src[tid + (2 * k) * 256];
        float2 b = src[tid + (2 * k + 1) * 256];
        px2[k] = (v2f){a.x, b.x};
        py2[k] = (v2f){a.y, b.y};
        md2[k] = (v2f){1e10f, 1e10f};
    }
    float2 c0 = src[0];
    if (tid == 0) centl[0] = c0;

    unsigned baseu = 0xFFFFFFFFu - (unsigned)tid;
    float c1x = c0.x, c1y = c0.y, c2x = 0.0f, c2y = 0.0f;
    bool two = false;
    int it = 1;
    unsigned rc = 0;
    while (it < M) {
        int par = (int)(rc & 1u); ++rc;
        // ---- packed md update by pending center(s); rn per half == scalar rn
        v2f vcx = (v2f){c1x, c1x}, vcy = (v2f){c1y, c1y};
#pragma unroll
        for (int k = 0; k < PP2; ++k) {
            v2f dx = px2[k] - vcx, dy = py2[k] - vcy;
            v2f d2 = (dx * dx) + (dy * dy);          // contract off => exact
            md2[k] = __builtin_elementwise_min(md2[k], d2);
        }
        if (two) {
            v2f wcx = (v2f){c2x, c2x}, wcy = (v2f){c2y, c2y};
#pragma unroll
            for (int k = 0; k < PP2; ++k) {
                v2f dx = px2[k] - wcx, dy = py2[k] - wcy;
                v2f d2 = (dx * dx) + (dy * dy);
                md2[k] = __builtin_elementwise_min(md2[k], d2);
            }
        }
        // ---- per-lane top-2: sorted-pair leaves + (max,second) merge tree
        unsigned long long TA[PP2], TB[PP2];
#pragma unroll
        for (int k = 0; k < PP2; ++k) {
            unsigned long long k0 =
                ((unsigned long long)__float_as_uint(md2[k].x) << 32)
                | (unsigned long long)(baseu - (unsigned)(2 * k) * 256u);
            unsigned long long k1 =
                ((unsigned long long)__float_as_uint(md2[k].y) << 32)
                | (unsigned long long)(baseu - (unsigned)(2 * k + 1) * 256u);
            bool g = k1 > k0;
            TA[k] = g ? k1 : k0;
            TB[k] = g ? k0 : k1;
        }
#pragma unroll
        for (int st = 1; st < PP2; st <<= 1) {
#pragma unroll
            for (int k = 0; k < PP2; k += 2 * st) {
                // merge (TA[k],TB[k]) with (TA[k+st],TB[k+st]); keys unique
                bool g = TA[k + st] > TA[k];
                unsigned long long nt = g ? TA[k + st] : TA[k];
                unsigned long long lt = g ? TA[k] : TA[k + st];   // losing top
                unsigned long long ws = g ? TB[k + st] : TB[k];   // winner 2nd
                TA[k] = nt;
                TB[k] = ws > lt ? ws : lt;
            }
        }
        unsigned long long t1 = TA[0], t2 = TB[0];
        // ---- wave pair ladder -> lane 63 (verbatim R0) ----
        pairc<0x111>(t1, t2); pairc<0x112>(t1, t2); pairc<0x114>(t1, t2);
        pairc<0x118>(t1, t2); pairc<0x142>(t1, t2); pairc<0x143>(t1, t2);
        if (lane == 63)
            slk[par][wv] = make_uint4((unsigned)t1, (unsigned)(t1 >> 32),
                                      (unsigned)t2, (unsigned)(t2 >> 32));
        __syncthreads();                   // the only barrier per round
        // ---- cross-wave quad butterfly: all lanes -> global (top1, top2)
        uint4 e = slk[par][lane & 3];
        unsigned long long a1 = ((unsigned long long)e.y << 32) | (unsigned long long)e.x;
        unsigned long long a2 = ((unsigned long long)e.w << 32) | (unsigned long long)e.z;
        pairc<0xB1>(a1, a2);               // quad xor1
        pairc<0x4E>(a1, a2);               // quad xor2
        int jw = (int)(0xFFFFFFFFu - (unsigned)a1);
        int jr = (int)(0xFFFFFFFFu - (unsigned)a2);
        float mdr = __uint_as_float((unsigned)(a2 >> 32));
        float2 wpt = PTSl[jw];             // uniform broadcast LDS reads
        float2 rpt = PTSl[jr];
        float ddx = rpt.x - wpt.x, ddy = rpt.y - wpt.y;
        float dd = (ddx * ddx) + (ddy * ddy);    // contract off => exact rn
        bool dbl = (it + 1 < M) && (dd >= mdr);  // uniform
        if (tid == 0) { centl[it] = wpt; if (dbl) centl[it + 1] = rpt; }
        c1x = wpt.x; c1y = wpt.y; c2x = rpt.x; c2y = rpt.y;
        two = dbl;
        it += dbl ? 2 : 1;
    }
}

// ---------------------------------------------------------------------------
// Fused FPS stage1 (4096 -> 2048) + stage2 (2048 -> 512); stage2 input is
// stage1's LDS-resident cent1. 256 threads (4 waves, 1/SIMD).
// ---------------------------------------------------------------------------
__global__ __launch_bounds__(256, 1) void k_fps_fused(
    const float2* __restrict__ pos, float* __restrict__ p1out,
    float* __restrict__ p2out)
{
    __shared__ float2 PTS[NN];            // 32 KB (gather source, stage 1)
    __shared__ float2 cent1[M1];          // 16 KB
    __shared__ float2 cent2[M2];          // 4 KB
    __shared__ uint4 slk[2][4];           // 128 B parity pair buffers
    int tid = threadIdx.x, lane = tid & 63, wv = tid >> 6;
    const float2* p = pos + (size_t)blockIdx.x * NN;

    for (int i = tid; i < NN; i += 256) PTS[i] = p[i];
    __syncthreads();                      // PTS complete

    fps_core<M1, NN / 256>(p, PTS, cent1, slk, tid, lane, wv);
    __syncthreads();                      // cent1 complete
    float2* o1 = (float2*)(p1out + (size_t)blockIdx.x * M1 * 2);
    for (int i = tid; i < M1; i += 256) o1[i] = cent1[i];

    fps_core<M2, M1 / 256>(cent1, cent1, cent2, slk, tid, lane, wv);
    __syncthreads();                      // cent2 complete
    float2* o2 = (float2*)(p2out + (size_t)blockIdx.x * M2 * 2);
    for (int i = tid; i < M2; i += 256) o2[i] = cent2[i];
}

// ---------------------------------------------------------------------------
// Set abstraction: h[i,f] = max_{j: d2(j,i)<=r2} y[j,f]  -  ctr_i @ W_rel.
// ---------------------------------------------------------------------------
__global__ __launch_bounds__(256) void k_sa(
    const float2* __restrict__ candpos, const float* __restrict__ y,
    const float* __restrict__ ctr, const float* __restrict__ W,
    int NP, int F, int relrow, float r2, float* __restrict__ hout)
{
    __shared__ int cnt;
    __shared__ int list[4096];
    int tid = threadIdx.x;
    int b = blockIdx.y;
    size_t crow = (size_t)b * gridDim.x + blockIdx.x;
    if (tid == 0) cnt = 0;
    __syncthreads();
    float cx = ctr[crow * 2], cy = ctr[crow * 2 + 1];
    const float2* cp = candpos + (size_t)b * NP;
    for (int j = tid; j < NP; j += 256) {
        float2 pj = cp[j];
        float d2 = d2_exact(pj.x - cx, pj.y - cy);
        if (d2 <= r2) { int t = atomicAdd(&cnt, 1); list[t] = j; }
    }
    __syncthreads();
    int n = cnt;
    for (int f = tid; f < F; f += 256) {
        float m = -3.0e38f;
        for (int t = 0; t < n; ++t)
            m = fmaxf(m, y[((size_t)b * NP + list[t]) * F + f]);
        float ct = cx * W[(size_t)relrow * F + f] + cy * W[(size_t)(relrow + 1) * F + f];
        hout[crow * F + f] = m - ct;
    }
}

// ---------------------------------------------------------------------------
// y2[j,f] = h1_j @ c2W[0:64] + pos_j @ c2W[64:66] + c2b
// ---------------------------------------------------------------------------
__global__ __launch_bounds__(128) void k_y2(
    const float* __restrict__ h1, const float* __restrict__ p1,
    const float* __restrict__ W, const float* __restrict__ bb,
    float* __restrict__ y2)
{
    __shared__ float sh[64];
    size_t row = blockIdx.x;
    int f = threadIdx.x;
    if (f < 64) sh[f] = h1[row * 64 + f];
    __syncthreads();
    float acc = bb[f] + p1[row * 2] * W[64 * 128 + f]
              + p1[row * 2 + 1] * W[65 * 128 + f];
#pragma unroll
    for (int c = 0; c < 64; ++c) acc += sh[c] * W[c * 128 + f];
    y2[row * 128 + f] = acc;
}

// ---------------------------------------------------------------------------
// g[i,f] = [h2_i, pos_i] @ c3W + c3b; partial max over 8 rows/thread.
// ---------------------------------------------------------------------------
__global__ __launch_bounds__(256) void k_g(
    const float* __restrict__ h2, const float* __restrict__ p2,
    const float* __restrict__ W3, const float* __restrict__ b3,
    float* __restrict__ part)
{
    int f = blockIdx.x * 256 + threadIdx.x;
    int b = blockIdx.z;
    int i0 = blockIdx.y * 8;
    float acc[8];
    float bbv = b3[f];
#pragma unroll
    for (int ii = 0; ii < 8; ++ii) acc[ii] = bbv;
    const float* hrow = h2 + ((size_t)b * M2 + i0) * 128;
    for (int c = 0; c < 128; ++c) {
        float w = W3[(size_t)c * 1024 + f];
#pragma unroll
        for (int ii = 0; ii < 8; ++ii) acc[ii] += hrow[ii * 128 + c] * w;
    }
    float wx = W3[(size_t)128 * 1024 + f];
    float wy = W3[(size_t)129 * 1024 + f];
    const float* prow = p2 + ((size_t)b * M2 + i0) * 2;
    float m = -3.0e38f;
#pragma unroll
    for (int ii = 0; ii < 8; ++ii) {
        float g = acc[ii] + prow[ii * 2] * wx + prow[ii * 2 + 1] * wy;
        m = fmaxf(m, g);
    }
    part[((size_t)b * 64 + blockIdx.y) * 1024 + f] = m;
}

__global__ __launch_bounds__(256) void k_gmax(const float* __restrict__ part,
                                              float* __restrict__ outg)
{
    int f = blockIdx.x * 256 + threadIdx.x;   // 0..4095
    int b = f >> 10, fl = f & 1023;
    float m = -3.0e38f;
#pragma unroll 8
    for (int ig = 0; ig < 64; ++ig)
        m = fmaxf(m, part[((size_t)b * 64 + ig) * 1024 + fl]);
    outg[f] = m;
}

extern "C" void kernel_launch(void* const* d_in, const int* in_sizes, int n_in,
                              void* d_out, int out_size, void* d_ws, size_t ws_size,
                              hipStream_t stream)
{
    const float* x    = (const float*)d_in[0];
    const float* zon  = (const float*)d_in[1];
    const float* lfW1 = (const float*)d_in[2];
    const float* lfb1 = (const float*)d_in[3];
    const float* lfW2 = (const float*)d_in[4];
    const float* lfb2 = (const float*)d_in[5];
    const float* c1W  = (const float*)d_in[6];
    const float* c1b  = (const float*)d_in[7];
    const float* c2W  = (const float*)d_in[8];
    const float* c2b  = (const float*)d_in[9];
    const float* c3W  = (const float*)d_in[10];
    const float* c3b  = (const float*)d_in[11];
    float* out = (float*)d_out;

    // Workspace (fp32). "big" (4 MB) reused: y1 -> y2 -> part.
    char* w = (char*)d_ws;
    float* big = (float*)w;                    w += (size_t)BB * NN * 64 * 4;   // 4 MB
    float* p1  = (float*)w;                    w += (size_t)BB * M1 * 2 * 4;
    float* h1  = (float*)w;                    w += (size_t)BB * M1 * 64 * 4;   // 2 MB
    float* p2  = (float*)w;                    w += (size_t)BB * M2 * 2 * 4;
    float* h2  = (float*)w;                    w += (size_t)BB * M2 * 128 * 4;  // 1 MB
    float* y1 = big, * y2 = big, * part = big;

    k_lf_y1<<<BB * NN / 4, 256, 0, stream>>>((const float2*)x, zon, lfW1, lfb1,
                                             lfW2, lfb2, c1W, c1b, out, y1);
    k_fps_fused<<<BB, 256, 0, stream>>>((const float2*)x, p1, p2);
    k_sa<<<dim3(M1, BB), 256, 0, stream>>>((const float2*)x, y1, p1, c1W,
                                           NN, 64, 65, 0.25f, h1);
    k_y2<<<BB * M1, 128, 0, stream>>>(h1, p1, c2W, c2b, y2);
    k_sa<<<dim3(M2, BB), 256, 0, stream>>>((const float2*)p1, y2, p2, c2W,
                                           M1, 128, 64, 1.0f, h2);
    k_g<<<dim3(4, 64, BB), 256, 0, stream>>>(h2, p2, c3W, c3b, part);
    k_gmax<<<16, 256, 0, stream>>>(part, out + (size_t)BB * NN * 64);
}

// Round 7
// 1527.593 us; speedup vs baseline: 1.9178x; 1.2064x over previous
//
#include <hip/hip_runtime.h>

// Inputs: fp32. Outputs: fp32 (established round 3: PASSED).

constexpr int BB = 4;
constexpr int NN = 4096;
constexpr int M1 = 2048;
constexpr int M2 = 512;

typedef float v2f __attribute__((ext_vector_type(2)));

// Exact fp32 squared distance matching numpy's (dx*dx) + (dy*dy), no fma contraction.
__device__ __forceinline__ float d2_exact(float dx, float dy) {
    return __fadd_rn(__fmul_rn(dx, dx), __fmul_rn(dy, dy));
}

// DPP with bound_ctrl=1 (invalid source lanes read 0 — zero keys always lose,
// all real keys > 0). Wave ladder (R0-proven): 0x111/0x112/0x114/0x118
// row_shr 1/2/4/8, 0x142 row_bcast15, 0x143 row_bcast31 -> result at lane 63.
// Quad levels (R6-proven): 0xB1 = quad_perm [1,0,3,2] (xor1), 0x4E =
// quad_perm [2,3,0,1] (xor2) — butterfly, result in ALL lanes.
template<int CTRL>
__device__ __forceinline__ unsigned long long dpp64z(unsigned long long v) {
    unsigned lo = (unsigned)__builtin_amdgcn_update_dpp(0, (int)(unsigned)v, CTRL, 0xF, 0xF, true);
    unsigned hi = (unsigned)__builtin_amdgcn_update_dpp(0, (int)(unsigned)(v >> 32), CTRL, 0xF, 0xF, true);
    return ((unsigned long long)hi << 32) | (unsigned long long)lo;
}
// (top1, top2) u64 pair combine with CTRL partner pair. Keys unique. (Proven.)
template<int CTRL>
__device__ __forceinline__ void pairc(unsigned long long& t1, unsigned long long& t2) {
    unsigned long long o1 = dpp64z<CTRL>(t1);
    unsigned long long o2 = dpp64z<CTRL>(t2);
    bool g = o1 > t1;
    unsigned long long m1 = g ? o1 : t1;
    unsigned long long sm = g ? t1 : o1;
    unsigned long long cn = g ? o2 : t2;
    t2 = cn > sm ? cn : sm;
    t1 = m1;
}

// ---------------------------------------------------------------------------
// FPS core: R0's proven structure (4 waves, 16 pts/lane packed scan, top-2
// speculation, parity-buffered single barrier per round). Two uniform cuts:
//  (1) per-lane top-2 scan runs in FLOAT domain with strict > (ascending
//      slot order == first-index tie-break of the u64 keys: equal md keeps
//      the earlier slot; demotion carries its index). u64 keys built once.
//  (2) cross-wave combine via quad_perm butterfly (R6-proven): one b128 read
//      + 2 quad merges leave the GLOBAL top-2 in every lane -> no readlanes.
// Bit-exact vs reference scan:
//   md[j] = fmin(md[j], d2_exact(j, c)); argmax w/ FIRST-index tie-break via
//   unique u64 key = bits(md)<<32 | (0xFFFFFFFF - j).
// If d2_exact(r1, w1) >= md_r1 the next reference pick is exactly r1 (all
// other keys < key_r1; updates only lower md; ties resolve by ~j) -> emit 2.
// ---------------------------------------------------------------------------
template<int M, int PPT>
__device__ __forceinline__ void fps_core(
    const float2* __restrict__ src, const float2* __restrict__ PTSl,
    float2* __restrict__ centl, uint4 (&slk)[2][4],
    int tid, int lane, int wv)
{
#pragma clang fp contract(off)
    constexpr int PP2 = PPT / 2;
    v2f px2[PP2], py2[PP2], md2[PP2];
#pragma unroll
    for (int k = 0; k < PP2; ++k) {
        float2 a = src[tid + (2 * k) * 256];
        float2 b = src[tid + (2 * k + 1) * 256];
        px2[k] = (v2f){a.x, b.x};
        py2[k] = (v2f){a.y, b.y};
        md2[k] = (v2f){1e10f, 1e10f};
    }
    float2 c0 = src[0];
    if (tid == 0) centl[0] = c0;

    unsigned baseu = 0xFFFFFFFFu - (unsigned)tid;
    float c1x = c0.x, c1y = c0.y, c2x = 0.0f, c2y = 0.0f;
    bool two = false;
    int it = 1;
    unsigned rc = 0;
    while (it < M) {
        int par = (int)(rc & 1u); ++rc;
        // ---- packed md update by pending center(s); rn per half == scalar rn
        v2f vcx = (v2f){c1x, c1x}, vcy = (v2f){c1y, c1y};
#pragma unroll
        for (int k = 0; k < PP2; ++k) {
            v2f dx = px2[k] - vcx, dy = py2[k] - vcy;
            v2f d2 = (dx * dx) + (dy * dy);          // contract off => exact
            md2[k] = __builtin_elementwise_min(md2[k], d2);
        }
        if (two) {
            v2f wcx = (v2f){c2x, c2x}, wcy = (v2f){c2y, c2y};
#pragma unroll
            for (int k = 0; k < PP2; ++k) {
                v2f dx = px2[k] - wcx, dy = py2[k] - wcy;
                v2f d2 = (dx * dx) + (dy * dy);
                md2[k] = __builtin_elementwise_min(md2[k], d2);
            }
        }
        // ---- per-lane top-2, float domain (strict > == first-index ties)
        float t1f = -1.0f, t2f = -1.0f;
        unsigned i1 = 0u, i2 = 0u;
#pragma unroll
        for (int s = 0; s < PPT; ++s) {
            float mq = (s & 1) ? md2[s >> 1].y : md2[s >> 1].x;
            unsigned io = baseu - (unsigned)(s * 256);
            bool g1 = mq > t1f;
            bool g2 = mq > t2f;
            t2f = g1 ? t1f : (g2 ? mq : t2f);
            i2  = g1 ? i1  : (g2 ? io : i2);
            t1f = g1 ? mq : t1f;
            i1  = g1 ? io : i1;
        }
        unsigned long long t1 =
            ((unsigned long long)__float_as_uint(t1f) << 32) | (unsigned long long)i1;
        unsigned long long t2 =
            ((unsigned long long)__float_as_uint(t2f) << 32) | (unsigned long long)i2;
        // ---- wave pair ladder -> lane 63 (verbatim R0) ----
        pairc<0x111>(t1, t2); pairc<0x112>(t1, t2); pairc<0x114>(t1, t2);
        pairc<0x118>(t1, t2); pairc<0x142>(t1, t2); pairc<0x143>(t1, t2);
        if (lane == 63)
            slk[par][wv] = make_uint4((unsigned)t1, (unsigned)(t1 >> 32),
                                      (unsigned)t2, (unsigned)(t2 >> 32));
        __syncthreads();                   // the only barrier per round
        // ---- cross-wave quad butterfly: all lanes -> global (top1, top2)
        uint4 e = slk[par][lane & 3];
        unsigned long long a1 = ((unsigned long long)e.y << 32) | (unsigned long long)e.x;
        unsigned long long a2 = ((unsigned long long)e.w << 32) | (unsigned long long)e.z;
        pairc<0xB1>(a1, a2);               // quad xor1
        pairc<0x4E>(a1, a2);               // quad xor2
        int jw = (int)(0xFFFFFFFFu - (unsigned)a1);
        int jr = (int)(0xFFFFFFFFu - (unsigned)a2);
        float mdr = __uint_as_float((unsigned)(a2 >> 32));
        float2 wpt = PTSl[jw];             // uniform broadcast LDS reads
        float2 rpt = PTSl[jr];
        float ddx = rpt.x - wpt.x, ddy = rpt.y - wpt.y;
        float dd = (ddx * ddx) + (ddy * ddy);    // contract off => exact rn
        bool dbl = (it + 1 < M) && (dd >= mdr);  // uniform
        if (tid == 0) { centl[it] = wpt; if (dbl) centl[it + 1] = rpt; }
        c1x = wpt.x; c1y = wpt.y; c2x = rpt.x; c2y = rpt.y;
        two = dbl;
        it += dbl ? 2 : 1;
    }
}

// ---------------------------------------------------------------------------
// Fused kernel: blocks [0, BB) run the serial FPS (stage1 4096->2048 +
// stage2 2048->512); blocks [BB, BB + BB*NN/4) run the lf/y1 dense math on
// otherwise-idle CUs, overlapping the ~1.5 ms FPS chain.
//   lf = tanh(tanh(x@W1+b1)@W2+b2); y1 = [lf, zones, pos] @ c1W + c1b.
// lf blocks alias their 2 KB of shared memory into PTS (separate blocks ->
// separate LDS allocations; no interaction).
// ---------------------------------------------------------------------------
__global__ __launch_bounds__(256, 1) void k_fps_lf(
    const float2* __restrict__ pos, float* __restrict__ p1out,
    float* __restrict__ p2out,
    const float* __restrict__ zones,
    const float* __restrict__ W1, const float* __restrict__ b1,
    const float* __restrict__ W2, const float* __restrict__ b2,
    const float* __restrict__ c1W, const float* __restrict__ c1b,
    float* __restrict__ out_lf, float* __restrict__ y1)
{
    __shared__ float2 PTS[NN];            // 32 KB (fps gather source / lf scratch)
    __shared__ float2 cent1[M1];          // 16 KB
    __shared__ float2 cent2[M2];          // 4 KB
    __shared__ uint4 slk[2][4];           // 128 B parity pair buffers
    int tid = threadIdx.x, lane = tid & 63, wv = tid >> 6;

    if (blockIdx.x >= (unsigned)BB) {
        // ---------------- lf / y1 path (verbatim k_lf_y1, LDS aliased) ----
        float* sh = (float*)PTS;          // sh[4][64]
        float* sl = sh + 256;             // sl[4][64]
        int p = tid >> 6, f = tid & 63;
        size_t pt = (size_t)(blockIdx.x - BB) * 4 + p;
        float2 xv = pos[pt];
        float hid = tanhf(xv.x * W1[f] + xv.y * W1[64 + f] + b1[f]);
        sh[p * 64 + f] = hid;
        __syncthreads();
        float acc = b2[f];
#pragma unroll
        for (int c = 0; c < 64; ++c) acc += sh[p * 64 + c] * W2[c * 64 + f];
        float lf = tanhf(acc);
        sl[p * 64 + f] = lf;
        out_lf[pt * 64 + f] = lf;
        __syncthreads();
        float acc2 = c1b[f] + zones[pt] * c1W[64 * 64 + f]
                   + xv.x * c1W[65 * 64 + f] + xv.y * c1W[66 * 64 + f];
#pragma unroll
        for (int c = 0; c < 64; ++c) acc2 += sl[p * 64 + c] * c1W[c * 64 + f];
        y1[pt * 64 + f] = acc2;
        return;
    }

    // -------------------- FPS path (blocks 0..BB-1) -----------------------
    const float2* p = pos + (size_t)blockIdx.x * NN;
    for (int i = tid; i < NN; i += 256) PTS[i] = p[i];
    __syncthreads();                      // PTS complete

    fps_core<M1, NN / 256>(p, PTS, cent1, slk, tid, lane, wv);
    __syncthreads();                      // cent1 complete
    float2* o1 = (float2*)(p1out + (size_t)blockIdx.x * M1 * 2);
    for (int i = tid; i < M1; i += 256) o1[i] = cent1[i];

    fps_core<M2, M1 / 256>(cent1, cent1, cent2, slk, tid, lane, wv);
    __syncthreads();                      // cent2 complete
    float2* o2 = (float2*)(p2out + (size_t)blockIdx.x * M2 * 2);
    for (int i = tid; i < M2; i += 256) o2[i] = cent2[i];
}

// ---------------------------------------------------------------------------
// Set abstraction: h[i,f] = max_{j: d2(j,i)<=r2} y[j,f]  -  ctr_i @ W_rel.
// ---------------------------------------------------------------------------
__global__ __launch_bounds__(256) void k_sa(
    const float2* __restrict__ candpos, const float* __restrict__ y,
    const float* __restrict__ ctr, const float* __restrict__ W,
    int NP, int F, int relrow, float r2, float* __restrict__ hout)
{
    __shared__ int cnt;
    __shared__ int list[4096];
    int tid = threadIdx.x;
    int b = blockIdx.y;
    size_t crow = (size_t)b * gridDim.x + blockIdx.x;
    if (tid == 0) cnt = 0;
    __syncthreads();
    float cx = ctr[crow * 2], cy = ctr[crow * 2 + 1];
    const float2* cp = candpos + (size_t)b * NP;
    for (int j = tid; j < NP; j += 256) {
        float2 pj = cp[j];
        float d2 = d2_exact(pj.x - cx, pj.y - cy);
        if (d2 <= r2) { int t = atomicAdd(&cnt, 1); list[t] = j; }
    }
    __syncthreads();
    int n = cnt;
    for (int f = tid; f < F; f += 256) {
        float m = -3.0e38f;
        for (int t = 0; t < n; ++t)
            m = fmaxf(m, y[((size_t)b * NP + list[t]) * F + f]);
        float ct = cx * W[(size_t)relrow * F + f] + cy * W[(size_t)(relrow + 1) * F + f];
        hout[crow * F + f] = m - ct;
    }
}

// ---------------------------------------------------------------------------
// y2[j,f] = h1_j @ c2W[0:64] + pos_j @ c2W[64:66] + c2b
// ---------------------------------------------------------------------------
__global__ __launch_bounds__(128) void k_y2(
    const float* __restrict__ h1, const float* __restrict__ p1,
    const float* __restrict__ W, const float* __restrict__ bb,
    float* __restrict__ y2)
{
    __shared__ float sh[64];
    size_t row = blockIdx.x;
    int f = threadIdx.x;
    if (f < 64) sh[f] = h1[row * 64 + f];
    __syncthreads();
    float acc = bb[f] + p1[row * 2] * W[64 * 128 + f]
              + p1[row * 2 + 1] * W[65 * 128 + f];
#pragma unroll
    for (int c = 0; c < 64; ++c) acc += sh[c] * W[c * 128 + f];
    y2[row * 128 + f] = acc;
}

// ---------------------------------------------------------------------------
// g[i,f] = [h2_i, pos_i] @ c3W + c3b; partial max over 8 rows/thread.
// ---------------------------------------------------------------------------
__global__ __launch_bounds__(256) void k_g(
    const float* __restrict__ h2, const float* __restrict__ p2,
    const float* __restrict__ W3, const float* __restrict__ b3,
    float* __restrict__ part)
{
    int f = blockIdx.x * 256 + threadIdx.x;
    int b = blockIdx.z;
    int i0 = blockIdx.y * 8;
    float acc[8];
    float bbv = b3[f];
#pragma unroll
    for (int ii = 0; ii < 8; ++ii) acc[ii] = bbv;
    const float* hrow = h2 + ((size_t)b * M2 + i0) * 128;
    for (int c = 0; c < 128; ++c) {
        float w = W3[(size_t)c * 1024 + f];
#pragma unroll
        for (int ii = 0; ii < 8; ++ii) acc[ii] += hrow[ii * 128 + c] * w;
    }
    float wx = W3[(size_t)128 * 1024 + f];
    float wy = W3[(size_t)129 * 1024 + f];
    const float* prow = p2 + ((size_t)b * M2 + i0) * 2;
    float m = -3.0e38f;
#pragma unroll
    for (int ii = 0; ii < 8; ++ii) {
        float g = acc[ii] + prow[ii * 2] * wx + prow[ii * 2 + 1] * wy;
        m = fmaxf(m, g);
    }
    part[((size_t)b * 64 + blockIdx.y) * 1024 + f] = m;
}

__global__ __launch_bounds__(256) void k_gmax(const float* __restrict__ part,
                                              float* __restrict__ outg)
{
    int f = blockIdx.x * 256 + threadIdx.x;   // 0..4095
    int b = f >> 10, fl = f & 1023;
    float m = -3.0e38f;
#pragma unroll 8
    for (int ig = 0; ig < 64; ++ig)
        m = fmaxf(m, part[((size_t)b * 64 + ig) * 1024 + fl]);
    outg[f] = m;
}

extern "C" void kernel_launch(void* const* d_in, const int* in_sizes, int n_in,
                              void* d_out, int out_size, void* d_ws, size_t ws_size,
                              hipStream_t stream)
{
    const float* x    = (const float*)d_in[0];
    const float* zon  = (const float*)d_in[1];
    const float* lfW1 = (const float*)d_in[2];
    const float* lfb1 = (const float*)d_in[3];
    const float* lfW2 = (const float*)d_in[4];
    const float* lfb2 = (const float*)d_in[5];
    const float* c1W  = (const float*)d_in[6];
    const float* c1b  = (const float*)d_in[7];
    const float* c2W  = (const float*)d_in[8];
    const float* c2b  = (const float*)d_in[9];
    const float* c3W  = (const float*)d_in[10];
    const float* c3b  = (const float*)d_in[11];
    float* out = (float*)d_out;

    // Workspace (fp32). "big" (4 MB) reused: y1 -> y2 -> part.
    char* w = (char*)d_ws;
    float* big = (float*)w;                    w += (size_t)BB * NN * 64 * 4;   // 4 MB
    float* p1  = (float*)w;                    w += (size_t)BB * M1 * 2 * 4;
    float* h1  = (float*)w;                    w += (size_t)BB * M1 * 64 * 4;   // 2 MB
    float* p2  = (float*)w;                    w += (size_t)BB * M2 * 2 * 4;
    float* h2  = (float*)w;                    w += (size_t)BB * M2 * 128 * 4;  // 1 MB
    float* y1 = big, * y2 = big, * part = big;

    // FPS (blocks 0..3) runs concurrently with lf/y1 (blocks 4..4099).
    k_fps_lf<<<BB + BB * NN / 4, 256, 0, stream>>>(
        (const float2*)x, p1, p2, zon, lfW1, lfb1, lfW2, lfb2, c1W, c1b, out, y1);
    k_sa<<<dim3(M1, BB), 256, 0, stream>>>((const float2*)x, y1, p1, c1W,
                                           NN, 64, 65, 0.25f, h1);
    k_y2<<<BB * M1, 128, 0, stream>>>(h1, p1, c2W, c2b, y2);
    k_sa<<<dim3(M2, BB), 256, 0, stream>>>((const float2*)p1, y2, p2, c2W,
                                           M1, 128, 64, 1.0f, h2);
    k_g<<<dim3(4, 64, BB), 256, 0, stream>>>(h2, p2, c3W, c3b, part);
    k_gmax<<<16, 256, 0, stream>>>(part, out + (size_t)BB * NN * 64);
}

// Round 8
// 1458.013 us; speedup vs baseline: 2.0093x; 1.0477x over previous
//
#include <hip/hip_runtime.h>

// Inputs: fp32. Outputs: fp32 (established round 3: PASSED).

constexpr int BB = 4;
constexpr int NN = 4096;
constexpr int M1 = 2048;
constexpr int M2 = 512;

typedef float v2f __attribute__((ext_vector_type(2)));

// Exact fp32 squared distance matching numpy's (dx*dx) + (dy*dy), no fma contraction.
__device__ __forceinline__ float d2_exact(float dx, float dy) {
    return __fadd_rn(__fmul_rn(dx, dx), __fmul_rn(dy, dy));
}

// DPP with bound_ctrl=1 (invalid source lanes read 0 — zero keys always lose,
// all real keys > 0). Wave ladder (R0-proven): 0x111/0x112/0x114/0x118
// row_shr 1/2/4/8, 0x142 row_bcast15, 0x143 row_bcast31 -> result at lane 63.
// Quad levels (R6/R7-proven): 0xB1 = quad_perm [1,0,3,2] (xor1), 0x4E =
// quad_perm [2,3,0,1] (xor2) — butterfly, result in ALL lanes.
template<int CTRL>
__device__ __forceinline__ unsigned long long dpp64z(unsigned long long v) {
    unsigned lo = (unsigned)__builtin_amdgcn_update_dpp(0, (int)(unsigned)v, CTRL, 0xF, 0xF, true);
    unsigned hi = (unsigned)__builtin_amdgcn_update_dpp(0, (int)(unsigned)(v >> 32), CTRL, 0xF, 0xF, true);
    return ((unsigned long long)hi << 32) | (unsigned long long)lo;
}
// (top1, top2) u64 pair combine with CTRL partner pair. Keys unique. (Proven.)
template<int CTRL>
__device__ __forceinline__ void pairc(unsigned long long& t1, unsigned long long& t2) {
    unsigned long long o1 = dpp64z<CTRL>(t1);
    unsigned long long o2 = dpp64z<CTRL>(t2);
    bool g = o1 > t1;
    unsigned long long m1 = g ? o1 : t1;
    unsigned long long sm = g ? t1 : o1;
    unsigned long long cn = g ? o2 : t2;
    t2 = cn > sm ? cn : sm;
    t1 = m1;
}

// ---------------------------------------------------------------------------
// FPS core (R7, PASSED): 4 waves, 16 pts/lane packed scan, float-domain
// top-2 (strict > == first-index tie-break), top-2 speculation, parity
// buffers, single barrier per round, quad-butterfly cross-wave combine.
// Bit-exact vs reference scan:
//   md[j] = fmin(md[j], d2_exact(j, c)); argmax w/ FIRST-index tie-break via
//   unique u64 key = bits(md)<<32 | (0xFFFFFFFF - j).
// If d2_exact(r1, w1) >= md_r1 the next reference pick is exactly r1 -> emit 2.
// ---------------------------------------------------------------------------
template<int M, int PPT>
__device__ __forceinline__ void fps_core(
    const float2* __restrict__ src, const float2* __restrict__ PTSl,
    float2* __restrict__ centl, uint4 (&slk)[2][4],
    int tid, int lane, int wv)
{
#pragma clang fp contract(off)
    constexpr int PP2 = PPT / 2;
    v2f px2[PP2], py2[PP2], md2[PP2];
#pragma unroll
    for (int k = 0; k < PP2; ++k) {
        float2 a = src[tid + (2 * k) * 256];
        float2 b = src[tid + (2 * k + 1) * 256];
        px2[k] = (v2f){a.x, b.x};
        py2[k] = (v2f){a.y, b.y};
        md2[k] = (v2f){1e10f, 1e10f};
    }
    float2 c0 = src[0];
    if (tid == 0) centl[0] = c0;

    unsigned baseu = 0xFFFFFFFFu - (unsigned)tid;
    float c1x = c0.x, c1y = c0.y, c2x = 0.0f, c2y = 0.0f;
    bool two = false;
    int it = 1;
    unsigned rc = 0;
    while (it < M) {
        int par = (int)(rc & 1u); ++rc;
        // ---- packed md update by pending center(s); rn per half == scalar rn
        v2f vcx = (v2f){c1x, c1x}, vcy = (v2f){c1y, c1y};
#pragma unroll
        for (int k = 0; k < PP2; ++k) {
            v2f dx = px2[k] - vcx, dy = py2[k] - vcy;
            v2f d2 = (dx * dx) + (dy * dy);          // contract off => exact
            md2[k] = __builtin_elementwise_min(md2[k], d2);
        }
        if (two) {
            v2f wcx = (v2f){c2x, c2x}, wcy = (v2f){c2y, c2y};
#pragma unroll
            for (int k = 0; k < PP2; ++k) {
                v2f dx = px2[k] - wcx, dy = py2[k] - wcy;
                v2f d2 = (dx * dx) + (dy * dy);
                md2[k] = __builtin_elementwise_min(md2[k], d2);
            }
        }
        // ---- per-lane top-2, float domain (strict > == first-index ties)
        float t1f = -1.0f, t2f = -1.0f;
        unsigned i1 = 0u, i2 = 0u;
#pragma unroll
        for (int s = 0; s < PPT; ++s) {
            float mq = (s & 1) ? md2[s >> 1].y : md2[s >> 1].x;
            unsigned io = baseu - (unsigned)(s * 256);
            bool g1 = mq > t1f;
            bool g2 = mq > t2f;
            t2f = g1 ? t1f : (g2 ? mq : t2f);
            i2  = g1 ? i1  : (g2 ? io : i2);
            t1f = g1 ? mq : t1f;
            i1  = g1 ? io : i1;
        }
        unsigned long long t1 =
            ((unsigned long long)__float_as_uint(t1f) << 32) | (unsigned long long)i1;
        unsigned long long t2 =
            ((unsigned long long)__float_as_uint(t2f) << 32) | (unsigned long long)i2;
        // ---- wave pair ladder -> lane 63 ----
        pairc<0x111>(t1, t2); pairc<0x112>(t1, t2); pairc<0x114>(t1, t2);
        pairc<0x118>(t1, t2); pairc<0x142>(t1, t2); pairc<0x143>(t1, t2);
        if (lane == 63)
            slk[par][wv] = make_uint4((unsigned)t1, (unsigned)(t1 >> 32),
                                      (unsigned)t2, (unsigned)(t2 >> 32));
        __syncthreads();                   // the only barrier per round
        // ---- cross-wave quad butterfly: all lanes -> global (top1, top2)
        uint4 e = slk[par][lane & 3];
        unsigned long long a1 = ((unsigned long long)e.y << 32) | (unsigned long long)e.x;
        unsigned long long a2 = ((unsigned long long)e.w << 32) | (unsigned long long)e.z;
        pairc<0xB1>(a1, a2);               // quad xor1
        pairc<0x4E>(a1, a2);               // quad xor2
        int jw = (int)(0xFFFFFFFFu - (unsigned)a1);
        int jr = (int)(0xFFFFFFFFu - (unsigned)a2);
        float mdr = __uint_as_float((unsigned)(a2 >> 32));
        float2 wpt = PTSl[jw];             // uniform broadcast LDS reads
        float2 rpt = PTSl[jr];
        float ddx = rpt.x - wpt.x, ddy = rpt.y - wpt.y;
        float dd = (ddx * ddx) + (ddy * ddy);    // contract off => exact rn
        bool dbl = (it + 1 < M) && (dd >= mdr);  // uniform
        if (tid == 0) { centl[it] = wpt; if (dbl) centl[it + 1] = rpt; }
        c1x = wpt.x; c1y = wpt.y; c2x = rpt.x; c2y = rpt.y;
        two = dbl;
        it += dbl ? 2 : 1;
    }
}

// ---------------------------------------------------------------------------
// Kernel 1: blocks [0, BB) run FPS STAGE 1 only (4096 -> 2048) -> p1;
// blocks [BB, BB + BB*NN/4) run the lf/y1 dense math on idle CUs (R7-proven).
// ---------------------------------------------------------------------------
__global__ __launch_bounds__(256, 1) void k_fps1(
    const float2* __restrict__ pos, float* __restrict__ p1out,
    const float* __restrict__ zones,
    const float* __restrict__ W1, const float* __restrict__ b1,
    const float* __restrict__ W2, const float* __restrict__ b2,
    const float* __restrict__ c1W, const float* __restrict__ c1b,
    float* __restrict__ out_lf, float* __restrict__ y1)
{
    __shared__ float2 PTS[NN];            // 32 KB (fps gather source / lf scratch)
    __shared__ float2 cent1[M1];          // 16 KB
    __shared__ uint4 slk[2][4];           // 128 B parity pair buffers
    int tid = threadIdx.x, lane = tid & 63, wv = tid >> 6;

    if (blockIdx.x >= (unsigned)BB) {
        // ---------------- lf / y1 path (verbatim R7, LDS aliased) ---------
        float* sh = (float*)PTS;          // sh[4][64]
        float* sl = sh + 256;             // sl[4][64]
        int p = tid >> 6, f = tid & 63;
        size_t pt = (size_t)(blockIdx.x - BB) * 4 + p;
        float2 xv = pos[pt];
        float hid = tanhf(xv.x * W1[f] + xv.y * W1[64 + f] + b1[f]);
        sh[p * 64 + f] = hid;
        __syncthreads();
        float acc = b2[f];
#pragma unroll
        for (int c = 0; c < 64; ++c) acc += sh[p * 64 + c] * W2[c * 64 + f];
        float lf = tanhf(acc);
        sl[p * 64 + f] = lf;
        out_lf[pt * 64 + f] = lf;
        __syncthreads();
        float acc2 = c1b[f] + zones[pt] * c1W[64 * 64 + f]
                   + xv.x * c1W[65 * 64 + f] + xv.y * c1W[66 * 64 + f];
#pragma unroll
        for (int c = 0; c < 64; ++c) acc2 += sl[p * 64 + c] * c1W[c * 64 + f];
        y1[pt * 64 + f] = acc2;
        return;
    }

    // -------------------- FPS stage 1 (blocks 0..BB-1) --------------------
    const float2* p = pos + (size_t)blockIdx.x * NN;
    for (int i = tid; i < NN; i += 256) PTS[i] = p[i];
    __syncthreads();                      // PTS complete

    fps_core<M1, NN / 256>(p, PTS, cent1, slk, tid, lane, wv);
    __syncthreads();                      // cent1 complete
    float2* o1 = (float2*)(p1out + (size_t)blockIdx.x * M1 * 2);
    for (int i = tid; i < M1; i += 256) o1[i] = cent1[i];
}

// ---------------------------------------------------------------------------
// Kernel 2: blocks [0, BB) run FPS STAGE 2 (2048 -> 512) -> p2 (p1 reloaded
// from global into LDS); blocks [BB, BB + M1*BB) each compute ONE sa1 center
// row h1[crow, 0:64] (exact k_sa semantics: NP=NN, F=64, relrow=65, r2=0.25)
// — p1/y1 are complete after k_fps1, so these 8192 short blocks hide under
// the 511-round serial stage-2 chain on the otherwise-idle 252 CUs.
// ---------------------------------------------------------------------------
__global__ __launch_bounds__(256) void k_fps2_sa1(
    const float2* __restrict__ x, const float* __restrict__ p1,
    const float* __restrict__ y1, const float* __restrict__ c1W,
    float* __restrict__ p2out, float* __restrict__ h1)
{
    __shared__ float2 PTS2[M1];           // 16 KB stage2 points
    __shared__ float2 cent2[M2];          // 4 KB
    __shared__ uint4 slk[2][4];           // 128 B
    __shared__ int cnt;
    __shared__ int list[NN];              // 16 KB sa candidate list
    int tid = threadIdx.x, lane = tid & 63, wv = tid >> 6;

    if (blockIdx.x < (unsigned)BB) {
        // -------------------- FPS stage 2 ---------------------------------
        const float2* p1b = (const float2*)(p1 + (size_t)blockIdx.x * M1 * 2);
        for (int i = tid; i < M1; i += 256) PTS2[i] = p1b[i];
        __syncthreads();                  // PTS2 complete
        fps_core<M2, M1 / 256>(PTS2, PTS2, cent2, slk, tid, lane, wv);
        __syncthreads();                  // cent2 complete
        float2* o2 = (float2*)(p2out + (size_t)blockIdx.x * M2 * 2);
        for (int i = tid; i < M2; i += 256) o2[i] = cent2[i];
        return;
    }

    // -------------------- sa1: one center per block -----------------------
    int idx = (int)blockIdx.x - BB;       // 0 .. M1*BB-1
    int b = idx >> 11;                    // / M1 (M1 == 2048)
    size_t crow = (size_t)idx;            // == b*M1 + (idx % M1)
    if (tid == 0) cnt = 0;
    __syncthreads();
    float cx = p1[crow * 2], cy = p1[crow * 2 + 1];
    const float2* cp = x + (size_t)b * NN;
    for (int j = tid; j < NN; j += 256) {
        float2 pj = cp[j];
        float d2 = d2_exact(pj.x - cx, pj.y - cy);
        if (d2 <= 0.25f) { int t = atomicAdd(&cnt, 1); list[t] = j; }
    }
    __syncthreads();
    int n = cnt;
    for (int f = tid; f < 64; f += 256) {
        float m = -3.0e38f;
        for (int t = 0; t < n; ++t)
            m = fmaxf(m, y1[((size_t)b * NN + list[t]) * 64 + f]);
        float ct = cx * c1W[(size_t)65 * 64 + f] + cy * c1W[(size_t)66 * 64 + f];
        h1[crow * 64 + f] = m - ct;
    }
}

// ---------------------------------------------------------------------------
// Set abstraction (stage 2): h[i,f] = max_{j: d2<=r2} y[j,f] - ctr_i @ W_rel.
// ---------------------------------------------------------------------------
__global__ __launch_bounds__(256) void k_sa(
    const float2* __restrict__ candpos, const float* __restrict__ y,
    const float* __restrict__ ctr, const float* __restrict__ W,
    int NP, int F, int relrow, float r2, float* __restrict__ hout)
{
    __shared__ int cnt;
    __shared__ int list[4096];
    int tid = threadIdx.x;
    int b = blockIdx.y;
    size_t crow = (size_t)b * gridDim.x + blockIdx.x;
    if (tid == 0) cnt = 0;
    __syncthreads();
    float cx = ctr[crow * 2], cy = ctr[crow * 2 + 1];
    const float2* cp = candpos + (size_t)b * NP;
    for (int j = tid; j < NP; j += 256) {
        float2 pj = cp[j];
        float d2 = d2_exact(pj.x - cx, pj.y - cy);
        if (d2 <= r2) { int t = atomicAdd(&cnt, 1); list[t] = j; }
    }
    __syncthreads();
    int n = cnt;
    for (int f = tid; f < F; f += 256) {
        float m = -3.0e38f;
        for (int t = 0; t < n; ++t)
            m = fmaxf(m, y[((size_t)b * NP + list[t]) * F + f]);
        float ct = cx * W[(size_t)relrow * F + f] + cy * W[(size_t)(relrow + 1) * F + f];
        hout[crow * F + f] = m - ct;
    }
}

// ---------------------------------------------------------------------------
// y2[j,f] = h1_j @ c2W[0:64] + pos_j @ c2W[64:66] + c2b
// ---------------------------------------------------------------------------
__global__ __launch_bounds__(128) void k_y2(
    const float* __restrict__ h1, const float* __restrict__ p1,
    const float* __restrict__ W, const float* __restrict__ bb,
    float* __restrict__ y2)
{
    __shared__ float sh[64];
    size_t row = blockIdx.x;
    int f = threadIdx.x;
    if (f < 64) sh[f] = h1[row * 64 + f];
    __syncthreads();
    float acc = bb[f] + p1[row * 2] * W[64 * 128 + f]
              + p1[row * 2 + 1] * W[65 * 128 + f];
#pragma unroll
    for (int c = 0; c < 64; ++c) acc += sh[c] * W[c * 128 + f];
    y2[row * 128 + f] = acc;
}

// ---------------------------------------------------------------------------
// g[i,f] = [h2_i, pos_i] @ c3W + c3b; partial max over 8 rows/thread.
// ---------------------------------------------------------------------------
__global__ __launch_bounds__(256) void k_g(
    const float* __restrict__ h2, const float* __restrict__ p2,
    const float* __restrict__ W3, const float* __restrict__ b3,
    float* __restrict__ part)
{
    int f = blockIdx.x * 256 + threadIdx.x;
    int b = blockIdx.z;
    int i0 = blockIdx.y * 8;
    float acc[8];
    float bbv = b3[f];
#pragma unroll
    for (int ii = 0; ii < 8; ++ii) acc[ii] = bbv;
    const float* hrow = h2 + ((size_t)b * M2 + i0) * 128;
    for (int c = 0; c < 128; ++c) {
        float w = W3[(size_t)c * 1024 + f];
#pragma unroll
        for (int ii = 0; ii < 8; ++ii) acc[ii] += hrow[ii * 128 + c] * w;
    }
    float wx = W3[(size_t)128 * 1024 + f];
    float wy = W3[(size_t)129 * 1024 + f];
    const float* prow = p2 + ((size_t)b * M2 + i0) * 2;
    float m = -3.0e38f;
#pragma unroll
    for (int ii = 0; ii < 8; ++ii) {
        float g = acc[ii] + prow[ii * 2] * wx + prow[ii * 2 + 1] * wy;
        m = fmaxf(m, g);
    }
    part[((size_t)b * 64 + blockIdx.y) * 1024 + f] = m;
}

__global__ __launch_bounds__(256) void k_gmax(const float* __restrict__ part,
                                              float* __restrict__ outg)
{
    int f = blockIdx.x * 256 + threadIdx.x;   // 0..4095
    int b = f >> 10, fl = f & 1023;
    float m = -3.0e38f;
#pragma unroll 8
    for (int ig = 0; ig < 64; ++ig)
        m = fmaxf(m, part[((size_t)b * 64 + ig) * 1024 + fl]);
    outg[f] = m;
}

extern "C" void kernel_launch(void* const* d_in, const int* in_sizes, int n_in,
                              void* d_out, int out_size, void* d_ws, size_t ws_size,
                              hipStream_t stream)
{
    const float* x    = (const float*)d_in[0];
    const float* zon  = (const float*)d_in[1];
    const float* lfW1 = (const float*)d_in[2];
    const float* lfb1 = (const float*)d_in[3];
    const float* lfW2 = (const float*)d_in[4];
    const float* lfb2 = (const float*)d_in[5];
    const float* c1W  = (const float*)d_in[6];
    const float* c1b  = (const float*)d_in[7];
    const float* c2W  = (const float*)d_in[8];
    const float* c2b  = (const float*)d_in[9];
    const float* c3W  = (const float*)d_in[10];
    const float* c3b  = (const float*)d_in[11];
    float* out = (float*)d_out;

    // Workspace (fp32). "big" (4 MB) reused: y1 -> y2 -> part.
    char* w = (char*)d_ws;
    float* big = (float*)w;                    w += (size_t)BB * NN * 64 * 4;   // 4 MB
    float* p1  = (float*)w;                    w += (size_t)BB * M1 * 2 * 4;
    float* h1  = (float*)w;                    w += (size_t)BB * M1 * 64 * 4;   // 2 MB
    float* p2  = (float*)w;                    w += (size_t)BB * M2 * 2 * 4;
    float* h2  = (float*)w;                    w += (size_t)BB * M2 * 128 * 4;  // 1 MB
    float* y1 = big, * y2 = big, * part = big;

    // Stage-1 FPS (blocks 0..3) overlaps lf/y1 (blocks 4..4099).
    k_fps1<<<BB + BB * NN / 4, 256, 0, stream>>>(
        (const float2*)x, p1, zon, lfW1, lfb1, lfW2, lfb2, c1W, c1b, out, y1);
    // Stage-2 FPS (blocks 0..3) overlaps sa1 (blocks 4..8195).
    k_fps2_sa1<<<BB + BB * M1, 256, 0, stream>>>(
        (const float2*)x, p1, y1, c1W, p2, h1);
    k_y2<<<BB * M1, 128, 0, stream>>>(h1, p1, c2W, c2b, y2);
    k_sa<<<dim3(M2, BB), 256, 0, stream>>>((const float2*)p1, y2, p2, c2W,
                                           M1, 128, 64, 1.0f, h2);
    k_g<<<dim3(4, 64, BB), 256, 0, stream>>>(h2, p2, c3W, c3b, part);
    k_gmax<<<16, 256, 0, stream>>>(part, out + (size_t)BB * NN * 64);
}

// Round 9
// 1428.557 us; speedup vs baseline: 2.0507x; 1.0206x over previous
//
#include <hip/hip_runtime.h>

// Inputs: fp32. Outputs: fp32 (established round 3: PASSED).

constexpr int BB = 4;
constexpr int NN = 4096;
constexpr int M1 = 2048;
constexpr int M2 = 512;

typedef float v2f __attribute__((ext_vector_type(2)));

// Exact fp32 squared distance matching numpy's (dx*dx) + (dy*dy), no fma contraction.
__device__ __forceinline__ float d2_exact(float dx, float dy) {
    return __fadd_rn(__fmul_rn(dx, dx), __fmul_rn(dy, dy));
}

// DPP with bound_ctrl=1 (invalid source lanes read 0 — zero keys always lose,
// all real keys > 0). Wave ladder (R0-proven): 0x111/0x112/0x114/0x118
// row_shr 1/2/4/8, 0x142 row_bcast15, 0x143 row_bcast31 -> result at lane 63.
// Quad levels (R6/R7-proven): 0xB1 = quad_perm [1,0,3,2] (xor1), 0x4E =
// quad_perm [2,3,0,1] (xor2) — butterfly, result in ALL lanes.
template<int CTRL>
__device__ __forceinline__ unsigned long long dpp64z(unsigned long long v) {
    unsigned lo = (unsigned)__builtin_amdgcn_update_dpp(0, (int)(unsigned)v, CTRL, 0xF, 0xF, true);
    unsigned hi = (unsigned)__builtin_amdgcn_update_dpp(0, (int)(unsigned)(v >> 32), CTRL, 0xF, 0xF, true);
    return ((unsigned long long)hi << 32) | (unsigned long long)lo;
}
// (top1, top2) u64 pair combine with CTRL partner pair. Keys unique. (Proven.)
template<int CTRL>
__device__ __forceinline__ void pairc(unsigned long long& t1, unsigned long long& t2) {
    unsigned long long o1 = dpp64z<CTRL>(t1);
    unsigned long long o2 = dpp64z<CTRL>(t2);
    bool g = o1 > t1;
    unsigned long long m1 = g ? o1 : t1;
    unsigned long long sm = g ? t1 : o1;
    unsigned long long cn = g ? o2 : t2;
    t2 = cn > sm ? cn : sm;
    t1 = m1;
}

// ---------------------------------------------------------------------------
// FPS core (R7/R8, PASSED): 4 waves, 16 pts/lane packed scan, float-domain
// top-2 (strict > == first-index tie-break), top-2 speculation, parity
// buffers, single barrier per round, quad-butterfly cross-wave combine.
// Bit-exact vs reference scan:
//   md[j] = fmin(md[j], d2_exact(j, c)); argmax w/ FIRST-index tie-break via
//   unique u64 key = bits(md)<<32 | (0xFFFFFFFF - j).
// If d2_exact(r1, w1) >= md_r1 the next reference pick is exactly r1 -> emit 2.
// ---------------------------------------------------------------------------
template<int M, int PPT>
__device__ __forceinline__ void fps_core(
    const float2* __restrict__ src, const float2* __restrict__ PTSl,
    float2* __restrict__ centl, uint4 (&slk)[2][4],
    int tid, int lane, int wv)
{
#pragma clang fp contract(off)
    constexpr int PP2 = PPT / 2;
    v2f px2[PP2], py2[PP2], md2[PP2];
#pragma unroll
    for (int k = 0; k < PP2; ++k) {
        float2 a = src[tid + (2 * k) * 256];
        float2 b = src[tid + (2 * k + 1) * 256];
        px2[k] = (v2f){a.x, b.x};
        py2[k] = (v2f){a.y, b.y};
        md2[k] = (v2f){1e10f, 1e10f};
    }
    float2 c0 = src[0];
    if (tid == 0) centl[0] = c0;

    unsigned baseu = 0xFFFFFFFFu - (unsigned)tid;
    float c1x = c0.x, c1y = c0.y, c2x = 0.0f, c2y = 0.0f;
    bool two = false;
    int it = 1;
    unsigned rc = 0;
    while (it < M) {
        int par = (int)(rc & 1u); ++rc;
        // ---- packed md update by pending center(s); rn per half == scalar rn
        v2f vcx = (v2f){c1x, c1x}, vcy = (v2f){c1y, c1y};
#pragma unroll
        for (int k = 0; k < PP2; ++k) {
            v2f dx = px2[k] - vcx, dy = py2[k] - vcy;
            v2f d2 = (dx * dx) + (dy * dy);          // contract off => exact
            md2[k] = __builtin_elementwise_min(md2[k], d2);
        }
        if (two) {
            v2f wcx = (v2f){c2x, c2x}, wcy = (v2f){c2y, c2y};
#pragma unroll
            for (int k = 0; k < PP2; ++k) {
                v2f dx = px2[k] - wcx, dy = py2[k] - wcy;
                v2f d2 = (dx * dx) + (dy * dy);
                md2[k] = __builtin_elementwise_min(md2[k], d2);
            }
        }
        // ---- per-lane top-2, float domain (strict > == first-index ties)
        float t1f = -1.0f, t2f = -1.0f;
        unsigned i1 = 0u, i2 = 0u;
#pragma unroll
        for (int s = 0; s < PPT; ++s) {
            float mq = (s & 1) ? md2[s >> 1].y : md2[s >> 1].x;
            unsigned io = baseu - (unsigned)(s * 256);
            bool g1 = mq > t1f;
            bool g2 = mq > t2f;
            t2f = g1 ? t1f : (g2 ? mq : t2f);
            i2  = g1 ? i1  : (g2 ? io : i2);
            t1f = g1 ? mq : t1f;
            i1  = g1 ? io : i1;
        }
        unsigned long long t1 =
            ((unsigned long long)__float_as_uint(t1f) << 32) | (unsigned long long)i1;
        unsigned long long t2 =
            ((unsigned long long)__float_as_uint(t2f) << 32) | (unsigned long long)i2;
        // ---- wave pair ladder -> lane 63 ----
        pairc<0x111>(t1, t2); pairc<0x112>(t1, t2); pairc<0x114>(t1, t2);
        pairc<0x118>(t1, t2); pairc<0x142>(t1, t2); pairc<0x143>(t1, t2);
        if (lane == 63)
            slk[par][wv] = make_uint4((unsigned)t1, (unsigned)(t1 >> 32),
                                      (unsigned)t2, (unsigned)(t2 >> 32));
        __syncthreads();                   // the only barrier per round
        // ---- cross-wave quad butterfly: all lanes -> global (top1, top2)
        uint4 e = slk[par][lane & 3];
        unsigned long long a1 = ((unsigned long long)e.y << 32) | (unsigned long long)e.x;
        unsigned long long a2 = ((unsigned long long)e.w << 32) | (unsigned long long)e.z;
        pairc<0xB1>(a1, a2);               // quad xor1
        pairc<0x4E>(a1, a2);               // quad xor2
        int jw = (int)(0xFFFFFFFFu - (unsigned)a1);
        int jr = (int)(0xFFFFFFFFu - (unsigned)a2);
        float mdr = __uint_as_float((unsigned)(a2 >> 32));
        float2 wpt = PTSl[jw];             // uniform broadcast LDS reads
        float2 rpt = PTSl[jr];
        float ddx = rpt.x - wpt.x, ddy = rpt.y - wpt.y;
        float dd = (ddx * ddx) + (ddy * ddy);    // contract off => exact rn
        bool dbl = (it + 1 < M) && (dd >= mdr);  // uniform
        if (tid == 0) { centl[it] = wpt; if (dbl) centl[it + 1] = rpt; }
        c1x = wpt.x; c1y = wpt.y; c2x = rpt.x; c2y = rpt.y;
        two = dbl;
        it += dbl ? 2 : 1;
    }
}

// ---------------------------------------------------------------------------
// Kernel 1: blocks [0, BB) run FPS STAGE 1 (4096 -> 2048) -> p1; blocks
// [BB, BB + BB*NN/4) run lf/y1 dense math on idle CUs (R7/R8-proven).
// LDS padded past 80 KB so each FPS block owns its CU exclusively — lf
// blocks (3/CU at 50 KB) were stealing SIMD issue slots from the
// latency-critical FPS waves during the overlap window.
// ---------------------------------------------------------------------------
__global__ __launch_bounds__(256, 1) void k_fps1(
    const float2* __restrict__ pos, float* __restrict__ p1out,
    const float* __restrict__ zones,
    const float* __restrict__ W1, const float* __restrict__ b1,
    const float* __restrict__ W2, const float* __restrict__ b2,
    const float* __restrict__ c1W, const float* __restrict__ c1b,
    float* __restrict__ out_lf, float* __restrict__ y1)
{
    __shared__ float2 PTS[NN];            // 32 KB (fps gather source / lf scratch)
    __shared__ float2 cent1[M1];          // 16 KB
    __shared__ uint4 slk[2][4];           // 128 B parity pair buffers
    __shared__ float2 LPAD[4160];         // 32.5 KB occupancy pad (never used)
    int tid = threadIdx.x, lane = tid & 63, wv = tid >> 6;
    // opaque touch keeps LPAD allocated; blockIdx never equals 0xFFFFFFFF
    if (blockIdx.x == 0xFFFFFFFFu) { LPAD[0] = PTS[0]; p1out[0] = LPAD[0].x; }

    if (blockIdx.x >= (unsigned)BB) {
        // ---------------- lf / y1 path (verbatim R7/R8, LDS aliased) ------
        float* sh = (float*)PTS;          // sh[4][64]
        float* sl = sh + 256;             // sl[4][64]
        int p = tid >> 6, f = tid & 63;
        size_t pt = (size_t)(blockIdx.x - BB) * 4 + p;
        float2 xv = pos[pt];
        float hid = tanhf(xv.x * W1[f] + xv.y * W1[64 + f] + b1[f]);
        sh[p * 64 + f] = hid;
        __syncthreads();
        float acc = b2[f];
#pragma unroll
        for (int c = 0; c < 64; ++c) acc += sh[p * 64 + c] * W2[c * 64 + f];
        float lf = tanhf(acc);
        sl[p * 64 + f] = lf;
        out_lf[pt * 64 + f] = lf;
        __syncthreads();
        float acc2 = c1b[f] + zones[pt] * c1W[64 * 64 + f]
                   + xv.x * c1W[65 * 64 + f] + xv.y * c1W[66 * 64 + f];
#pragma unroll
        for (int c = 0; c < 64; ++c) acc2 += sl[p * 64 + c] * c1W[c * 64 + f];
        y1[pt * 64 + f] = acc2;
        return;
    }

    // -------------------- FPS stage 1 (blocks 0..BB-1) --------------------
    const float2* p = pos + (size_t)blockIdx.x * NN;
    for (int i = tid; i < NN; i += 256) PTS[i] = p[i];
    __syncthreads();                      // PTS complete

    fps_core<M1, NN / 256>(p, PTS, cent1, slk, tid, lane, wv);
    __syncthreads();                      // cent1 complete
    float2* o1 = (float2*)(p1out + (size_t)blockIdx.x * M1 * 2);
    for (int i = tid; i < M1; i += 256) o1[i] = cent1[i];
}

// ---------------------------------------------------------------------------
// Kernel 2: blocks [0, BB) run FPS STAGE 2 (2048 -> 512) -> p2; blocks
// [BB, BB + M1*BB) each compute ONE sa1 center row h1[crow] and — when
// fuse_y2 != 0 (workspace permits a non-aliased y2) — immediately the y2 row
// with k_y2's exact addition order, hidden under the 511-round stage-2 chain.
// ---------------------------------------------------------------------------
__global__ __launch_bounds__(256) void k_fps2_sa1(
    const float2* __restrict__ x, const float* __restrict__ p1,
    const float* __restrict__ y1, const float* __restrict__ c1W,
    const float* __restrict__ c2W, const float* __restrict__ c2b,
    float* __restrict__ p2out, float* __restrict__ h1,
    float* __restrict__ y2, int fuse_y2)
{
    __shared__ float2 PTS2[M1];           // 16 KB stage2 points
    __shared__ float2 cent2[M2];          // 4 KB
    __shared__ uint4 slk[2][4];           // 128 B
    __shared__ int cnt;
    __shared__ int list[NN];              // 16 KB sa candidate list
    __shared__ float h1row[64];           // staged h1 row for fused y2
    int tid = threadIdx.x, lane = tid & 63, wv = tid >> 6;

    if (blockIdx.x < (unsigned)BB) {
        // -------------------- FPS stage 2 ---------------------------------
        const float2* p1b = (const float2*)(p1 + (size_t)blockIdx.x * M1 * 2);
        for (int i = tid; i < M1; i += 256) PTS2[i] = p1b[i];
        __syncthreads();                  // PTS2 complete
        fps_core<M2, M1 / 256>(PTS2, PTS2, cent2, slk, tid, lane, wv);
        __syncthreads();                  // cent2 complete
        float2* o2 = (float2*)(p2out + (size_t)blockIdx.x * M2 * 2);
        for (int i = tid; i < M2; i += 256) o2[i] = cent2[i];
        return;
    }

    // -------------------- sa1: one center per block -----------------------
    int idx = (int)blockIdx.x - BB;       // 0 .. M1*BB-1
    int b = idx >> 11;                    // / M1 (M1 == 2048)
    size_t crow = (size_t)idx;            // == b*M1 + (idx % M1)
    if (tid == 0) cnt = 0;
    __syncthreads();
    float cx = p1[crow * 2], cy = p1[crow * 2 + 1];
    const float2* cp = x + (size_t)b * NN;
    for (int j = tid; j < NN; j += 256) {
        float2 pj = cp[j];
        float d2 = d2_exact(pj.x - cx, pj.y - cy);
        if (d2 <= 0.25f) { int t = atomicAdd(&cnt, 1); list[t] = j; }
    }
    __syncthreads();
    int n = cnt;
    for (int f = tid; f < 64; f += 256) {
        float m = -3.0e38f;
        for (int t = 0; t < n; ++t)
            m = fmaxf(m, y1[((size_t)b * NN + list[t]) * 64 + f]);
        float ct = cx * c1W[(size_t)65 * 64 + f] + cy * c1W[(size_t)66 * 64 + f];
        float h1v = m - ct;
        if (fuse_y2) h1row[f] = h1v;
        else h1[crow * 64 + f] = h1v;
    }
    if (fuse_y2) {                        // uniform kernel arg -> safe barrier
        __syncthreads();                  // h1row complete
        // exact k_y2 arithmetic/order: (bb + px*W64) + py*W65, then c=0..63
        for (int f = tid; f < 128; f += 256) {
            float acc = c2b[f] + cx * c2W[64 * 128 + f]
                      + cy * c2W[65 * 128 + f];
#pragma unroll
            for (int c = 0; c < 64; ++c) acc += h1row[c] * c2W[c * 128 + f];
            y2[crow * 128 + f] = acc;
        }
    }
}

// ---------------------------------------------------------------------------
// Set abstraction (stage 2): h[i,f] = max_{j: d2<=r2} y[j,f] - ctr_i @ W_rel.
// ---------------------------------------------------------------------------
__global__ __launch_bounds__(256) void k_sa(
    const float2* __restrict__ candpos, const float* __restrict__ y,
    const float* __restrict__ ctr, const float* __restrict__ W,
    int NP, int F, int relrow, float r2, float* __restrict__ hout)
{
    __shared__ int cnt;
    __shared__ int list[4096];
    int tid = threadIdx.x;
    int b = blockIdx.y;
    size_t crow = (size_t)b * gridDim.x + blockIdx.x;
    if (tid == 0) cnt = 0;
    __syncthreads();
    float cx = ctr[crow * 2], cy = ctr[crow * 2 + 1];
    const float2* cp = candpos + (size_t)b * NP;
    for (int j = tid; j < NP; j += 256) {
        float2 pj = cp[j];
        float d2 = d2_exact(pj.x - cx, pj.y - cy);
        if (d2 <= r2) { int t = atomicAdd(&cnt, 1); list[t] = j; }
    }
    __syncthreads();
    int n = cnt;
    for (int f = tid; f < F; f += 256) {
        float m = -3.0e38f;
        for (int t = 0; t < n; ++t)
            m = fmaxf(m, y[((size_t)b * NP + list[t]) * F + f]);
        float ct = cx * W[(size_t)relrow * F + f] + cy * W[(size_t)(relrow + 1) * F + f];
        hout[crow * F + f] = m - ct;
    }
}

// ---------------------------------------------------------------------------
// y2[j,f] = h1_j @ c2W[0:64] + pos_j @ c2W[64:66] + c2b  (fallback only)
// ---------------------------------------------------------------------------
__global__ __launch_bounds__(128) void k_y2(
    const float* __restrict__ h1, const float* __restrict__ p1,
    const float* __restrict__ W, const float* __restrict__ bb,
    float* __restrict__ y2)
{
    __shared__ float sh[64];
    size_t row = blockIdx.x;
    int f = threadIdx.x;
    if (f < 64) sh[f] = h1[row * 64 + f];
    __syncthreads();
    float acc = bb[f] + p1[row * 2] * W[64 * 128 + f]
              + p1[row * 2 + 1] * W[65 * 128 + f];
#pragma unroll
    for (int c = 0; c < 64; ++c) acc += sh[c] * W[c * 128 + f];
    y2[row * 128 + f] = acc;
}

// ---------------------------------------------------------------------------
// g[i,f] = [h2_i, pos_i] @ c3W + c3b; partial max over 8 rows/thread.
// ---------------------------------------------------------------------------
__global__ __launch_bounds__(256) void k_g(
    const float* __restrict__ h2, const float* __restrict__ p2,
    const float* __restrict__ W3, const float* __restrict__ b3,
    float* __restrict__ part)
{
    int f = blockIdx.x * 256 + threadIdx.x;
    int b = blockIdx.z;
    int i0 = blockIdx.y * 8;
    float acc[8];
    float bbv = b3[f];
#pragma unroll
    for (int ii = 0; ii < 8; ++ii) acc[ii] = bbv;
    const float* hrow = h2 + ((size_t)b * M2 + i0) * 128;
    for (int c = 0; c < 128; ++c) {
        float w = W3[(size_t)c * 1024 + f];
#pragma unroll
        for (int ii = 0; ii < 8; ++ii) acc[ii] += hrow[ii * 128 + c] * w;
    }
    float wx = W3[(size_t)128 * 1024 + f];
    float wy = W3[(size_t)129 * 1024 + f];
    const float* prow = p2 + ((size_t)b * M2 + i0) * 2;
    float m = -3.0e38f;
#pragma unroll
    for (int ii = 0; ii < 8; ++ii) {
        float g = acc[ii] + prow[ii * 2] * wx + prow[ii * 2 + 1] * wy;
        m = fmaxf(m, g);
    }
    part[((size_t)b * 64 + blockIdx.y) * 1024 + f] = m;
}

__global__ __launch_bounds__(256) void k_gmax(const float* __restrict__ part,
                                              float* __restrict__ outg)
{
    int f = blockIdx.x * 256 + threadIdx.x;   // 0..4095
    int b = f >> 10, fl = f & 1023;
    float m = -3.0e38f;
#pragma unroll 8
    for (int ig = 0; ig < 64; ++ig)
        m = fmaxf(m, part[((size_t)b * 64 + ig) * 1024 + fl]);
    outg[f] = m;
}

extern "C" void kernel_launch(void* const* d_in, const int* in_sizes, int n_in,
                              void* d_out, int out_size, void* d_ws, size_t ws_size,
                              hipStream_t stream)
{
    const float* x    = (const float*)d_in[0];
    const float* zon  = (const float*)d_in[1];
    const float* lfW1 = (const float*)d_in[2];
    const float* lfb1 = (const float*)d_in[3];
    const float* lfW2 = (const float*)d_in[4];
    const float* lfb2 = (const float*)d_in[5];
    const float* c1W  = (const float*)d_in[6];
    const float* c1b  = (const float*)d_in[7];
    const float* c2W  = (const float*)d_in[8];
    const float* c2b  = (const float*)d_in[9];
    const float* c3W  = (const float*)d_in[10];
    const float* c3b  = (const float*)d_in[11];
    float* out = (float*)d_out;

    // Sizes (bytes)
    const size_t szY1 = (size_t)BB * NN * 64 * 4;    // 4 MB
    const size_t szP1 = (size_t)BB * M1 * 2 * 4;
    const size_t szH1 = (size_t)BB * M1 * 64 * 4;    // 2 MB
    const size_t szY2 = (size_t)BB * M1 * 128 * 4;   // 4 MB
    const size_t szP2 = (size_t)BB * M2 * 2 * 4;
    const size_t szH2 = (size_t)BB * M2 * 128 * 4;   // 1 MB

    // Fused layout needs y2 NOT aliasing y1 (sa1 blocks read y1 while y2 is
    // written). Fall back to the R8 layout + k_y2 when ws is too small.
    bool fuse = ws_size >= szY1 + szP1 + szY2 + szP2 + szH2;

    char* w = (char*)d_ws;
    float* y1 = (float*)w;                     w += szY1;   // also reused: part
    float* p1 = (float*)w;                     w += szP1;
    float *h1, *y2;
    if (fuse) {
        h1 = nullptr;
        y2 = (float*)w;                        w += szY2;
    } else {
        h1 = (float*)w;                        w += szH1;
        y2 = y1;                               // R8 alias (y1 dead by k_y2)
    }
    float* p2 = (float*)w;                     w += szP2;
    float* h2 = (float*)w;                     w += szH2;
    float* part = y1;                          // y1 dead after kernel 2

    // Stage-1 FPS (blocks 0..3, exclusive CUs) overlaps lf/y1 (blocks 4..).
    k_fps1<<<BB + BB * NN / 4, 256, 0, stream>>>(
        (const float2*)x, p1, zon, lfW1, lfb1, lfW2, lfb2, c1W, c1b, out, y1);
    // Stage-2 FPS (blocks 0..3) overlaps sa1 (+fused y2) (blocks 4..8195).
    k_fps2_sa1<<<BB + BB * M1, 256, 0, stream>>>(
        (const float2*)x, p1, y1, c1W, c2W, c2b, p2,
        fuse ? p1 /*unused*/ : h1, y2, fuse ? 1 : 0);
    if (!fuse)
        k_y2<<<BB * M1, 128, 0, stream>>>(h1, p1, c2W, c2b, y2);
    k_sa<<<dim3(M2, BB), 256, 0, stream>>>((const float2*)p1, y2, p2, c2W,
                                           M1, 128, 64, 1.0f, h2);
    k_g<<<dim3(4, 64, BB), 256, 0, stream>>>(h2, p2, c3W, c3b, part);
    k_gmax<<<16, 256, 0, stream>>>(part, out + (size_t)BB * NN * 64);
}